// Round 8
// baseline (84.740 us; speedup 1.0000x reference)
//
#include <hip/hip_runtime.h>
#include <hip/hip_bf16.h>
#include <math.h>

#define N 4096
#define FIN 512
#define HID 256
#define HEADS 4
#define DHEAD 256
#define FOUT 1024
#define TOPK 29
#define CAP 64    // per-row candidate capacity (mean ~20.5, sd ~4.5)
#define CAPC 96   // per-column source capacity (in-degree mean ~20.4)

typedef __attribute__((ext_vector_type(8))) short short8;
typedef __attribute__((ext_vector_type(4))) float f32x4;
typedef __hip_bfloat16 bf16;

__device__ __forceinline__ float bflo(unsigned int u) {
  return __uint_as_float(u << 16);
}
__device__ __forceinline__ float bfhi(unsigned int u) {
  return __uint_as_float(u & 0xffff0000u);
}

// ---- block-per-row scan + fused prep converts + al2/ar2 + top-29 select ----
// phase 0: grid-stride bf16 conversions + attn-vector projection
//          alr2[0..1023] = al2[h][k] = sum_d gat_W[k, h*256+d] * attn_l[h,d]
//          alr2[1024..2047] = ar2 likewise
// phase 1: row scan; 4 independent adj4 loads/thread, cond sim4, LDS compaction
// phase 2: rank top-29 among positives, push source into column lists
__global__ __launch_bounds__(256) void scan_kernel(
    const float* __restrict__ h, const float* __restrict__ W_trans,
    const float* __restrict__ gat_W, const float* __restrict__ attn_l,
    const float* __restrict__ attn_r, const float* __restrict__ adj,
    const float* __restrict__ simlar, bf16* __restrict__ hb,
    bf16* __restrict__ Wtb, bf16* __restrict__ gWtb,
    float* __restrict__ alr2, int* __restrict__ colcnt,
    int* __restrict__ colsrc) {
  const int t = threadIdx.x;
  const int s = blockIdx.x;
  // ---- phase 0 ----
  {
    const int H4 = N * FIN / 4;  // 524288 float4 of h
    const int WT = HID * FIN;    // 131072 Wtb elements [HID][FIN]
    const int GT = FOUT * HID;   // 262144 gWtb elements [FOUT][HID]
    const int AL = 2 * HEADS * HID;  // 2048 projected attn entries
    const int total = H4 + WT + GT + AL;
    const int stride = gridDim.x * 256;
    for (int i = s * 256 + t; i < total; i += stride) {
      if (i < H4) {
        const float4 v = reinterpret_cast<const float4*>(h)[i];
        bf16 tmp[4];
        tmp[0] = __float2bfloat16(v.x);
        tmp[1] = __float2bfloat16(v.y);
        tmp[2] = __float2bfloat16(v.z);
        tmp[3] = __float2bfloat16(v.w);
        *reinterpret_cast<ushort4*>(&hb[(size_t)i * 4]) =
            *reinterpret_cast<ushort4*>(tmp);
      } else if (i < H4 + WT) {
        const int j = i - H4;
        const int row = j >> 9, k = j & 511;  // [HID][FIN]
        Wtb[j] = __float2bfloat16(W_trans[(size_t)k * HID + row]);
      } else if (i < H4 + WT + GT) {
        const int j = i - H4 - WT;
        const int row = j >> 8, k = j & 255;  // [FOUT][HID]
        gWtb[j] = __float2bfloat16(gat_W[(size_t)k * FOUT + row]);
      } else {
        const int j = i - H4 - WT - GT;         // 0..2047
        const float* vec = (j < 1024) ? attn_l : attn_r;
        const int jj = j & 1023;
        const int hh = jj >> 8, k = jj & 255;   // head, hid-dim
        const float* wp = &gat_W[(size_t)k * FOUT + hh * DHEAD];
        const float* vp = &vec[hh * DHEAD];
        float acc = 0.f;
        for (int d = 0; d < DHEAD; ++d) acc = fmaf(wp[d], vp[d], acc);
        alr2[j] = acc;
      }
    }
  }
  // ---- phase 1: scan row s ----
  __shared__ float swv[CAP];
  __shared__ int swi[CAP];
  __shared__ int cnt;
  if (t == 0) cnt = 0;
  __syncthreads();
  const float4* rowadj = reinterpret_cast<const float4*>(adj) + (size_t)s * (N / 4);
  const float4* rowsim = reinterpret_cast<const float4*>(simlar) + (size_t)s * (N / 4);
  float4 a[4];
#pragma unroll
  for (int it = 0; it < 4; ++it) a[it] = rowadj[it * 256 + t];  // 4 loads in flight
#pragma unroll
  for (int it = 0; it < 4; ++it) {
    const int j = it * 256 + t;
    if (a[it].x > 0.f || a[it].y > 0.f || a[it].z > 0.f || a[it].w > 0.f) {
      const float4 s4 = rowsim[j];
      const float aa[4] = {a[it].x, a[it].y, a[it].z, a[it].w};
      const float ss[4] = {s4.x, s4.y, s4.z, s4.w};
#pragma unroll
      for (int c = 0; c < 4; ++c) {
        if (aa[c] > 0.f && ss[c] > 0.f) {
          const int p = atomicAdd(&cnt, 1);
          if (p < CAP) {
            swv[p] = ss[c];
            swi[p] = j * 4 + c;
          }
        }
      }
    }
  }
  __syncthreads();
  // ---- phase 2: rank select (value-based -> order-independent) ----
  const int C = min(cnt, CAP);
  if (t < C) {
    const float x = swv[t];
    int rk = 0;
    for (int jj = 0; jj < C; ++jj) rk += (swv[jj] > x);
    if (rk < TOPK) {
      const int d = swi[t];
      const int p = atomicAdd(&colcnt[d], 1);
      if (p < CAPC) colsrc[(size_t)d * CAPC + p] = s;
    }
  }
}

// ------- bf16 MFMA GEMM (64x64 tile, BK=64): xb = lrelu(hb @ Wtb^T) ---------
__global__ __launch_bounds__(256) void gemm_mfma64(const bf16* __restrict__ A,
                                                   const bf16* __restrict__ Bt,
                                                   bf16* __restrict__ Cb,
                                                   int M, int Nn, int K) {
  __shared__ bf16 As[64][72];  // +8 pad
  __shared__ bf16 Bs[64][72];
  const int t = threadIdx.x;
  const int bm = blockIdx.x * 64, bn = blockIdx.y * 64;
  const int w = t >> 6, lane = t & 63, r = lane & 15, g = lane >> 4;
  const int m = t >> 2, c0 = (t & 3) * 8;
  f32x4 acc[4] = {};
  for (int k0 = 0; k0 < K; k0 += 64) {
    const bf16* arow = &A[(size_t)(bm + m) * K + k0];
    const bf16* brow = &Bt[(size_t)(bn + m) * K + k0];
    *reinterpret_cast<int4*>(&As[m][c0]) = *reinterpret_cast<const int4*>(&arow[c0]);
    *reinterpret_cast<int4*>(&As[m][c0 + 32]) = *reinterpret_cast<const int4*>(&arow[c0 + 32]);
    *reinterpret_cast<int4*>(&Bs[m][c0]) = *reinterpret_cast<const int4*>(&brow[c0]);
    *reinterpret_cast<int4*>(&Bs[m][c0 + 32]) = *reinterpret_cast<const int4*>(&brow[c0 + 32]);
    __syncthreads();
    const short8 a0 = *reinterpret_cast<short8*>(&As[w * 16 + r][g * 8]);
    const short8 a1 = *reinterpret_cast<short8*>(&As[w * 16 + r][32 + g * 8]);
#pragma unroll
    for (int j = 0; j < 4; ++j) {
      const short8 b0 = *reinterpret_cast<short8*>(&Bs[j * 16 + r][g * 8]);
      const short8 b1 = *reinterpret_cast<short8*>(&Bs[j * 16 + r][32 + g * 8]);
      acc[j] = __builtin_amdgcn_mfma_f32_16x16x32_bf16(a0, b0, acc[j], 0, 0, 0);
      acc[j] = __builtin_amdgcn_mfma_f32_16x16x32_bf16(a1, b1, acc[j], 0, 0, 0);
    }
    __syncthreads();
  }
#pragma unroll
  for (int j = 0; j < 4; ++j)
#pragma unroll
    for (int q = 0; q < 4; ++q) {
      const int row = bm + w * 16 + g * 4 + q;
      const int col = bn + j * 16 + r;
      float v = acc[j][q];
      v = v >= 0.f ? v : 0.01f * v;  // lrelu(0.01)
      Cb[(size_t)row * Nn + col] = __float2bfloat16(v);
    }
}

// ------- bf16 MFMA GEMM (128x128 tile, BK=32): featb = xb @ gWtb^T ----------
// 4 waves; wave w owns rows [w*32, w*32+32), all 128 cols: acc[2][8].
__global__ __launch_bounds__(256) void gemm_mfma128(const bf16* __restrict__ A,
                                                    const bf16* __restrict__ Bt,
                                                    bf16* __restrict__ Cb,
                                                    int M, int Nn, int K) {
  __shared__ bf16 As[128][40];  // +8 pad
  __shared__ bf16 Bs[128][40];
  const int t = threadIdx.x;
  const int bm = blockIdx.x * 128, bn = blockIdx.y * 128;
  const int w = t >> 6, lane = t & 63, r = lane & 15, g = lane >> 4;
  const int m = t >> 1, c0 = (t & 1) * 16;  // staging: 128 rows x 2 x 16-elem
  f32x4 acc[2][8] = {};
  for (int k0 = 0; k0 < K; k0 += 32) {
    const bf16* arow = &A[(size_t)(bm + m) * K + k0 + c0];
    const bf16* brow = &Bt[(size_t)(bn + m) * K + k0 + c0];
    *reinterpret_cast<int4*>(&As[m][c0]) = *reinterpret_cast<const int4*>(arow);
    *reinterpret_cast<int4*>(&As[m][c0 + 8]) = *reinterpret_cast<const int4*>(arow + 8);
    *reinterpret_cast<int4*>(&Bs[m][c0]) = *reinterpret_cast<const int4*>(brow);
    *reinterpret_cast<int4*>(&Bs[m][c0 + 8]) = *reinterpret_cast<const int4*>(brow + 8);
    __syncthreads();
    const short8 a0 = *reinterpret_cast<short8*>(&As[w * 32 + r][g * 8]);
    const short8 a1 = *reinterpret_cast<short8*>(&As[w * 32 + 16 + r][g * 8]);
#pragma unroll
    for (int j = 0; j < 8; ++j) {
      const short8 b = *reinterpret_cast<short8*>(&Bs[j * 16 + r][g * 8]);
      acc[0][j] = __builtin_amdgcn_mfma_f32_16x16x32_bf16(a0, b, acc[0][j], 0, 0, 0);
      acc[1][j] = __builtin_amdgcn_mfma_f32_16x16x32_bf16(a1, b, acc[1][j], 0, 0, 0);
    }
    __syncthreads();
  }
#pragma unroll
  for (int i = 0; i < 2; ++i)
#pragma unroll
    for (int j = 0; j < 8; ++j)
#pragma unroll
      for (int q = 0; q < 4; ++q) {
        const int row = bm + w * 32 + i * 16 + g * 4 + q;
        const int col = bn + j * 16 + r;
        Cb[(size_t)row * Nn + col] = __float2bfloat16(acc[i][j][q]);
      }
}

// ---- el/er from xb and projected attn vectors: el[n,h] = xb[n,:]·al2[h,:] --
__global__ __launch_bounds__(256) void elr2_kernel(const bf16* __restrict__ xb,
                                                   const float* __restrict__ alr2,
                                                   float* __restrict__ el,
                                                   float* __restrict__ er) {
  __shared__ float alrs[2048];
  const int t = threadIdx.x;
  for (int i = t; i < 2048; i += 256) alrs[i] = alr2[i];
  __syncthreads();
  const int wv = t >> 6, lane = t & 63;
  const int n = blockIdx.x * 4 + wv;
  const uint2 v2 = *reinterpret_cast<const uint2*>(&xb[(size_t)n * HID + lane * 4]);
  const float xf[4] = {bflo(v2.x), bfhi(v2.x), bflo(v2.y), bfhi(v2.y)};
  float pl[4], pr[4];
#pragma unroll
  for (int hh = 0; hh < 4; ++hh) {
    const int base = hh * 256 + lane * 4;
    pl[hh] = xf[0] * alrs[base] + xf[1] * alrs[base + 1] +
             xf[2] * alrs[base + 2] + xf[3] * alrs[base + 3];
    pr[hh] = xf[0] * alrs[1024 + base] + xf[1] * alrs[1024 + base + 1] +
             xf[2] * alrs[1024 + base + 2] + xf[3] * alrs[1024 + base + 3];
  }
  for (int off = 32; off; off >>= 1) {
#pragma unroll
    for (int hh = 0; hh < 4; ++hh) {
      pl[hh] += __shfl_xor(pl[hh], off);
      pr[hh] += __shfl_xor(pr[hh], off);
    }
  }
  if (lane == 0) {
#pragma unroll
    for (int hh = 0; hh < 4; ++hh) {
      el[n * HEADS + hh] = pl[hh];
      er[n * HEADS + hh] = pr[hh];
    }
  }
}

// ---------------- per-column softmax + weighted bf16 feature gather ----------
// Block = 4 (column, dim-half) tasks of 64 lanes each; half = blockIdx&1,
// which matches XCD parity under round-robin dispatch -> each XCD's L2 only
// caches one 4MB half of featb. Softmax is redundantly computed per half
// (deterministic identical results).
__global__ __launch_bounds__(256) void agg_kernel(const int* __restrict__ colcnt,
                                                  const int* __restrict__ colsrc,
                                                  const float* __restrict__ el,
                                                  const float* __restrict__ er,
                                                  const bf16* __restrict__ featb,
                                                  const float* __restrict__ bias,
                                                  float* __restrict__ out) {
  __shared__ int tmp[4][CAPC];
  __shared__ int slist[4][CAPC];
  __shared__ float pbuf[4][2][CAPC];
  const int t = threadIdx.x;
  const int grp = t >> 6;   // 4 tasks per block
  const int lane = t & 63;  // lane within task
  const int hf = blockIdx.x & 1;                 // dim-half (XCD parity)
  const int d = (blockIdx.x >> 1) * 4 + grp;     // destination column
  const int C = min(colcnt[d], CAPC);
  for (int i = lane; i < C; i += 64) tmp[grp][i] = colsrc[(size_t)d * CAPC + i];
  __syncthreads();
  // rank-sort ascending (unique ids -> bijective, deterministic vs atomics)
  for (int i = lane; i < C; i += 64) {
    const int v = tmp[grp][i];
    int rk = 0;
    for (int j = 0; j < C; ++j) rk += (tmp[grp][j] < v);
    slist[grp][rk] = v;
  }
  __syncthreads();
  const int sl = lane >> 5;       // sub-head within half
  const int h = hf * 2 + sl;      // global head
  const int hl = lane & 31;
  const float er_dh = er[d * HEADS + h];
  // pass A: e values -> pbuf, running max (32-lane subgroup)
  float m = -INFINITY;
  for (int i = hl; i < C; i += 32) {
    float e = el[slist[grp][i] * HEADS + h] + er_dh;
    e = e >= 0.f ? e : 0.2f * e;
    pbuf[grp][sl][i] = e;
    m = fmaxf(m, e);
  }
#pragma unroll
  for (int off = 16; off; off >>= 1) m = fmaxf(m, __shfl_xor(m, off));
  // pass B: exp in place, denom reduce
  float dsum = 0.f;
  for (int i = hl; i < C; i += 32) {
    const float p = __expf(pbuf[grp][sl][i] - m);
    pbuf[grp][sl][i] = p;
    dsum += p;
  }
#pragma unroll
  for (int off = 16; off; off >>= 1) dsum += __shfl_xor(dsum, off);
  __syncthreads();
  // pass C: weighted gather; 64 lanes x 16B = 1KB per (row, half)
  const size_t dimoff = hf * 512 + lane * 8;
  float acc[8] = {};
  int i = 0;
  for (; i + 2 <= C; i += 2) {
    const float p0 = pbuf[grp][sl][i];
    const float p1 = pbuf[grp][sl][i + 1];
    const uint4 v0 = *reinterpret_cast<const uint4*>(
        &featb[(size_t)slist[grp][i] * FOUT + dimoff]);
    const uint4 v1 = *reinterpret_cast<const uint4*>(
        &featb[(size_t)slist[grp][i + 1] * FOUT + dimoff]);
    acc[0] = fmaf(p0, bflo(v0.x), acc[0]);
    acc[1] = fmaf(p0, bfhi(v0.x), acc[1]);
    acc[2] = fmaf(p0, bflo(v0.y), acc[2]);
    acc[3] = fmaf(p0, bfhi(v0.y), acc[3]);
    acc[4] = fmaf(p0, bflo(v0.z), acc[4]);
    acc[5] = fmaf(p0, bfhi(v0.z), acc[5]);
    acc[6] = fmaf(p0, bflo(v0.w), acc[6]);
    acc[7] = fmaf(p0, bfhi(v0.w), acc[7]);
    acc[0] = fmaf(p1, bflo(v1.x), acc[0]);
    acc[1] = fmaf(p1, bfhi(v1.x), acc[1]);
    acc[2] = fmaf(p1, bflo(v1.y), acc[2]);
    acc[3] = fmaf(p1, bfhi(v1.y), acc[3]);
    acc[4] = fmaf(p1, bflo(v1.z), acc[4]);
    acc[5] = fmaf(p1, bfhi(v1.z), acc[5]);
    acc[6] = fmaf(p1, bflo(v1.w), acc[6]);
    acc[7] = fmaf(p1, bfhi(v1.w), acc[7]);
  }
  if (i < C) {
    const float p0 = pbuf[grp][sl][i];
    const uint4 v0 = *reinterpret_cast<const uint4*>(
        &featb[(size_t)slist[grp][i] * FOUT + dimoff]);
    acc[0] = fmaf(p0, bflo(v0.x), acc[0]);
    acc[1] = fmaf(p0, bfhi(v0.x), acc[1]);
    acc[2] = fmaf(p0, bflo(v0.y), acc[2]);
    acc[3] = fmaf(p0, bfhi(v0.y), acc[3]);
    acc[4] = fmaf(p0, bflo(v0.z), acc[4]);
    acc[5] = fmaf(p0, bfhi(v0.z), acc[5]);
    acc[6] = fmaf(p0, bflo(v0.w), acc[6]);
    acc[7] = fmaf(p0, bfhi(v0.w), acc[7]);
  }
  const float inv = C > 0 ? 1.f / dsum : 0.f;
  float o[8];
#pragma unroll
  for (int k = 0; k < 8; ++k) {
    const float r = acc[k] * inv + bias[dimoff + k];
    o[k] = r > 0.f ? r : expm1f(r);
  }
  float* op = &out[(size_t)d * FOUT + dimoff];
  *reinterpret_cast<float4*>(op) = make_float4(o[0], o[1], o[2], o[3]);
  *reinterpret_cast<float4*>(op + 4) = make_float4(o[4], o[5], o[6], o[7]);
}

extern "C" void kernel_launch(void* const* d_in, const int* in_sizes, int n_in,
                              void* d_out, int out_size, void* d_ws, size_t ws_size,
                              hipStream_t stream) {
  const float* h        = (const float*)d_in[0];
  const float* simlar   = (const float*)d_in[1];
  const float* adj      = (const float*)d_in[2];
  const float* W_trans  = (const float*)d_in[3];
  const float* gat_W    = (const float*)d_in[4];
  const float* attn_l   = (const float*)d_in[5];
  const float* attn_r   = (const float*)d_in[6];
  const float* gat_bias = (const float*)d_in[7];
  // sem_W1 / sem_b1 / sem_W2 unused: beta = softmax over singleton == 1 -> out == sem.
  float* out = (float*)d_out;

  char* ws = (char*)d_ws;
  const size_t MB = 1 << 20;
  bf16* hb    = (bf16*)(ws);                        // 4 MB   (N x FIN)
  bf16* Wtb   = (bf16*)(ws + 4 * MB);               // 256 KB (HID x FIN)
  bf16* gWtb  = (bf16*)(ws + 4 * MB + 512 * 1024);  // 512 KB (FOUT x HID)
  bf16* xb    = (bf16*)(ws + 5 * MB);               // 2 MB   (N x HID)
  float* el   = (float*)(ws + 7 * MB);              // 64 KB
  float* er   = (float*)(ws + 7 * MB + 65536);      // 64 KB
  float* alr2 = (float*)(ws + 7 * MB + 131072);     // 8 KB (al2 | ar2)
  bf16* featb = (bf16*)(ws + 8 * MB);               // 8 MB   (N x FOUT bf16)
  int* colcnt = (int*)(ws + 16 * MB);               // 16 KB
  int* colsrc = (int*)(ws + 17 * MB);               // 1.5 MB

  hipMemsetAsync(colcnt, 0, (size_t)N * sizeof(int), stream);
  scan_kernel<<<N, 256, 0, stream>>>(h, W_trans, gat_W, attn_l, attn_r, adj,
                                     simlar, hb, Wtb, gWtb, alr2, colcnt, colsrc);
  gemm_mfma64<<<dim3(N / 64, HID / 64), 256, 0, stream>>>(hb, Wtb, xb, N, HID, FIN);
  gemm_mfma128<<<dim3(N / 128, FOUT / 128), 256, 0, stream>>>(xb, gWtb, featb, N, FOUT, HID);
  elr2_kernel<<<N / 4, 256, 0, stream>>>(xb, alr2, el, er);
  agg_kernel<<<N / 2, 256, 0, stream>>>(colcnt, colsrc, el, er, featb, gat_bias, out);
}

// Round 9
// 76.499 us; speedup vs baseline: 1.1077x; 1.1077x over previous
//
#include <hip/hip_runtime.h>
#include <hip/hip_bf16.h>
#include <math.h>

#define N 4096
#define FIN 512
#define HID 256
#define HEADS 4
#define DHEAD 256
#define FOUT 1024
#define TOPK 29
#define CAP 64    // per-row candidate capacity (mean ~20.5, sd ~4.5)
#define CAPC 96   // per-column source capacity (in-degree mean ~20.4)

typedef __attribute__((ext_vector_type(8))) short short8;
typedef __attribute__((ext_vector_type(4))) float f32x4;
typedef __hip_bfloat16 bf16;

__device__ __forceinline__ float bflo(unsigned int u) {
  return __uint_as_float(u << 16);
}
__device__ __forceinline__ float bfhi(unsigned int u) {
  return __uint_as_float(u & 0xffff0000u);
}

// ---- init: zero colcnt + project attn vectors through gat_W ----------------
// alr2[j], j in [0,2048): j<1024 -> al2[h][k], else ar2[h][k]:
//   al2[h][k] = sum_d gat_W[k, h*256+d] * attn_l[h,d]
// 16 lanes per output, coalesced 64B/lane reads, shuffle reduce.
__global__ __launch_bounds__(256) void init_kernel(const float* __restrict__ gat_W,
                                                   const float* __restrict__ attn_l,
                                                   const float* __restrict__ attn_r,
                                                   float* __restrict__ alr2,
                                                   int* __restrict__ colcnt) {
  const int tid = blockIdx.x * 256 + threadIdx.x;
  if (tid < N) colcnt[tid] = 0;
  const int j = tid >> 4;  // 0..2047 at 128 blocks
  const int l16 = tid & 15;
  if (j < 2 * HEADS * HID) {
    const float* vec = (j < 1024) ? attn_l : attn_r;
    const int jj = j & 1023;
    const int hh = jj >> 8, k = jj & 255;
    const float4* wp = reinterpret_cast<const float4*>(
        &gat_W[(size_t)k * FOUT + hh * DHEAD + l16 * 16]);
    const float4* vp = reinterpret_cast<const float4*>(&vec[hh * DHEAD + l16 * 16]);
    float acc = 0.f;
#pragma unroll
    for (int q = 0; q < 4; ++q) {
      const float4 w4 = wp[q], v4 = vp[q];
      acc += w4.x * v4.x + w4.y * v4.y + w4.z * v4.z + w4.w * v4.w;
    }
#pragma unroll
    for (int off = 1; off < 16; off <<= 1) acc += __shfl_xor(acc, off);
    if (l16 == 0) alr2[j] = acc;
  }
}

// ---- block-per-row scan + fused prep converts + top-29 select --------------
// phase 0: grid-stride converts, all COALESCED reads (scattered bf16 writes)
// phase 1: row scan; 4 independent adj4 loads/thread, cond sim4, LDS compaction
// phase 2: rank top-29 among positives, push source into column lists
__global__ __launch_bounds__(256) void scan_kernel(
    const float* __restrict__ h, const float* __restrict__ W_trans,
    const float* __restrict__ gat_W, const float* __restrict__ adj,
    const float* __restrict__ simlar, bf16* __restrict__ hb,
    bf16* __restrict__ Wtb, bf16* __restrict__ gWtb,
    int* __restrict__ colcnt, int* __restrict__ colsrc) {
  const int t = threadIdx.x;
  const int s = blockIdx.x;
  // ---- phase 0 ----
  {
    const int H4 = N * FIN / 4;     // 524288 float4 of h
    const int WT4 = HID * FIN / 4;  // 32768 float4 of W_trans (natural order)
    const int GT4 = FOUT * HID / 4; // 65536 float4 of gat_W (natural order)
    const int total = H4 + WT4 + GT4;
    const int stride = gridDim.x * 256;
    for (int i = s * 256 + t; i < total; i += stride) {
      if (i < H4) {
        const float4 v = reinterpret_cast<const float4*>(h)[i];
        bf16 tmp[4];
        tmp[0] = __float2bfloat16(v.x);
        tmp[1] = __float2bfloat16(v.y);
        tmp[2] = __float2bfloat16(v.z);
        tmp[3] = __float2bfloat16(v.w);
        *reinterpret_cast<ushort4*>(&hb[(size_t)i * 4]) =
            *reinterpret_cast<ushort4*>(tmp);
      } else if (i < H4 + WT4) {
        // W_trans [FIN][HID] natural float4 read -> Wtb [HID][FIN] scattered
        const int j4 = i - H4;
        const float4 v = reinterpret_cast<const float4*>(W_trans)[j4];
        const int k = j4 >> 6;           // fin row 0..511
        const int c0 = (j4 & 63) * 4;    // hid col 0..255
        Wtb[(size_t)(c0 + 0) * FIN + k] = __float2bfloat16(v.x);
        Wtb[(size_t)(c0 + 1) * FIN + k] = __float2bfloat16(v.y);
        Wtb[(size_t)(c0 + 2) * FIN + k] = __float2bfloat16(v.z);
        Wtb[(size_t)(c0 + 3) * FIN + k] = __float2bfloat16(v.w);
      } else {
        // gat_W [HID][FOUT] natural float4 read -> gWtb [FOUT][HID] scattered
        const int j4 = i - H4 - WT4;
        const float4 v = reinterpret_cast<const float4*>(gat_W)[j4];
        const int k = j4 >> 8;           // hid row 0..255
        const int c0 = (j4 & 255) * 4;   // fout col 0..1023
        gWtb[(size_t)(c0 + 0) * HID + k] = __float2bfloat16(v.x);
        gWtb[(size_t)(c0 + 1) * HID + k] = __float2bfloat16(v.y);
        gWtb[(size_t)(c0 + 2) * HID + k] = __float2bfloat16(v.z);
        gWtb[(size_t)(c0 + 3) * HID + k] = __float2bfloat16(v.w);
      }
    }
  }
  // ---- phase 1: scan row s ----
  __shared__ float swv[CAP];
  __shared__ int swi[CAP];
  __shared__ int cnt;
  if (t == 0) cnt = 0;
  __syncthreads();
  const float4* rowadj = reinterpret_cast<const float4*>(adj) + (size_t)s * (N / 4);
  const float4* rowsim = reinterpret_cast<const float4*>(simlar) + (size_t)s * (N / 4);
  float4 a[4];
#pragma unroll
  for (int it = 0; it < 4; ++it) a[it] = rowadj[it * 256 + t];  // 4 loads in flight
#pragma unroll
  for (int it = 0; it < 4; ++it) {
    const int j = it * 256 + t;
    if (a[it].x > 0.f || a[it].y > 0.f || a[it].z > 0.f || a[it].w > 0.f) {
      const float4 s4 = rowsim[j];
      const float aa[4] = {a[it].x, a[it].y, a[it].z, a[it].w};
      const float ss[4] = {s4.x, s4.y, s4.z, s4.w};
#pragma unroll
      for (int c = 0; c < 4; ++c) {
        if (aa[c] > 0.f && ss[c] > 0.f) {
          const int p = atomicAdd(&cnt, 1);
          if (p < CAP) {
            swv[p] = ss[c];
            swi[p] = j * 4 + c;
          }
        }
      }
    }
  }
  __syncthreads();
  // ---- phase 2: rank select (value-based -> order-independent) ----
  const int C = min(cnt, CAP);
  if (t < C) {
    const float x = swv[t];
    int rk = 0;
    for (int jj = 0; jj < C; ++jj) rk += (swv[jj] > x);
    if (rk < TOPK) {
      const int d = swi[t];
      const int p = atomicAdd(&colcnt[d], 1);
      if (p < CAPC) colsrc[(size_t)d * CAPC + p] = s;
    }
  }
}

// ------- bf16 MFMA GEMM (64x64 tile, BK=64): xb = lrelu(hb @ Wtb^T) ---------
__global__ __launch_bounds__(256) void gemm_mfma64(const bf16* __restrict__ A,
                                                   const bf16* __restrict__ Bt,
                                                   bf16* __restrict__ Cb,
                                                   int M, int Nn, int K) {
  __shared__ bf16 As[64][72];  // +8 pad
  __shared__ bf16 Bs[64][72];
  const int t = threadIdx.x;
  const int bm = blockIdx.x * 64, bn = blockIdx.y * 64;
  const int w = t >> 6, lane = t & 63, r = lane & 15, g = lane >> 4;
  const int m = t >> 2, c0 = (t & 3) * 8;
  f32x4 acc[4] = {};
  for (int k0 = 0; k0 < K; k0 += 64) {
    const bf16* arow = &A[(size_t)(bm + m) * K + k0];
    const bf16* brow = &Bt[(size_t)(bn + m) * K + k0];
    *reinterpret_cast<int4*>(&As[m][c0]) = *reinterpret_cast<const int4*>(&arow[c0]);
    *reinterpret_cast<int4*>(&As[m][c0 + 32]) = *reinterpret_cast<const int4*>(&arow[c0 + 32]);
    *reinterpret_cast<int4*>(&Bs[m][c0]) = *reinterpret_cast<const int4*>(&brow[c0]);
    *reinterpret_cast<int4*>(&Bs[m][c0 + 32]) = *reinterpret_cast<const int4*>(&brow[c0 + 32]);
    __syncthreads();
    const short8 a0 = *reinterpret_cast<short8*>(&As[w * 16 + r][g * 8]);
    const short8 a1 = *reinterpret_cast<short8*>(&As[w * 16 + r][32 + g * 8]);
#pragma unroll
    for (int j = 0; j < 4; ++j) {
      const short8 b0 = *reinterpret_cast<short8*>(&Bs[j * 16 + r][g * 8]);
      const short8 b1 = *reinterpret_cast<short8*>(&Bs[j * 16 + r][32 + g * 8]);
      acc[j] = __builtin_amdgcn_mfma_f32_16x16x32_bf16(a0, b0, acc[j], 0, 0, 0);
      acc[j] = __builtin_amdgcn_mfma_f32_16x16x32_bf16(a1, b1, acc[j], 0, 0, 0);
    }
    __syncthreads();
  }
#pragma unroll
  for (int j = 0; j < 4; ++j)
#pragma unroll
    for (int q = 0; q < 4; ++q) {
      const int row = bm + w * 16 + g * 4 + q;
      const int col = bn + j * 16 + r;
      float v = acc[j][q];
      v = v >= 0.f ? v : 0.01f * v;  // lrelu(0.01)
      Cb[(size_t)row * Nn + col] = __float2bfloat16(v);
    }
}

// ------- bf16 MFMA GEMM (128x128 tile, BK=32): featb = xb @ gWtb^T ----------
// 4 waves; wave w owns rows [w*32, w*32+32), all 128 cols: acc[2][8].
__global__ __launch_bounds__(256) void gemm_mfma128(const bf16* __restrict__ A,
                                                    const bf16* __restrict__ Bt,
                                                    bf16* __restrict__ Cb,
                                                    int M, int Nn, int K) {
  __shared__ bf16 As[128][40];  // +8 pad
  __shared__ bf16 Bs[128][40];
  const int t = threadIdx.x;
  const int bm = blockIdx.x * 128, bn = blockIdx.y * 128;
  const int w = t >> 6, lane = t & 63, r = lane & 15, g = lane >> 4;
  const int m = t >> 1, c0 = (t & 1) * 16;  // staging: 128 rows x 2 x 16-elem
  f32x4 acc[2][8] = {};
  for (int k0 = 0; k0 < K; k0 += 32) {
    const bf16* arow = &A[(size_t)(bm + m) * K + k0 + c0];
    const bf16* brow = &Bt[(size_t)(bn + m) * K + k0 + c0];
    *reinterpret_cast<int4*>(&As[m][c0]) = *reinterpret_cast<const int4*>(arow);
    *reinterpret_cast<int4*>(&As[m][c0 + 8]) = *reinterpret_cast<const int4*>(arow + 8);
    *reinterpret_cast<int4*>(&Bs[m][c0]) = *reinterpret_cast<const int4*>(brow);
    *reinterpret_cast<int4*>(&Bs[m][c0 + 8]) = *reinterpret_cast<const int4*>(brow + 8);
    __syncthreads();
    const short8 a0 = *reinterpret_cast<short8*>(&As[w * 32 + r][g * 8]);
    const short8 a1 = *reinterpret_cast<short8*>(&As[w * 32 + 16 + r][g * 8]);
#pragma unroll
    for (int j = 0; j < 8; ++j) {
      const short8 b = *reinterpret_cast<short8*>(&Bs[j * 16 + r][g * 8]);
      acc[0][j] = __builtin_amdgcn_mfma_f32_16x16x32_bf16(a0, b, acc[0][j], 0, 0, 0);
      acc[1][j] = __builtin_amdgcn_mfma_f32_16x16x32_bf16(a1, b, acc[1][j], 0, 0, 0);
    }
    __syncthreads();
  }
#pragma unroll
  for (int i = 0; i < 2; ++i)
#pragma unroll
    for (int j = 0; j < 8; ++j)
#pragma unroll
      for (int q = 0; q < 4; ++q) {
        const int row = bm + w * 32 + i * 16 + g * 4 + q;
        const int col = bn + j * 16 + r;
        Cb[(size_t)row * Nn + col] = __float2bfloat16(acc[i][j][q]);
      }
}

// ---- el/er from xb and projected attn vectors: el[n,h] = xb[n,:]·al2[h,:] --
__global__ __launch_bounds__(256) void elr2_kernel(const bf16* __restrict__ xb,
                                                   const float* __restrict__ alr2,
                                                   float* __restrict__ el,
                                                   float* __restrict__ er) {
  __shared__ float alrs[2048];
  const int t = threadIdx.x;
  for (int i = t; i < 2048; i += 256) alrs[i] = alr2[i];
  __syncthreads();
  const int wv = t >> 6, lane = t & 63;
  const int n = blockIdx.x * 4 + wv;
  const uint2 v2 = *reinterpret_cast<const uint2*>(&xb[(size_t)n * HID + lane * 4]);
  const float xf[4] = {bflo(v2.x), bfhi(v2.x), bflo(v2.y), bfhi(v2.y)};
  float pl[4], pr[4];
#pragma unroll
  for (int hh = 0; hh < 4; ++hh) {
    const int base = hh * 256 + lane * 4;
    pl[hh] = xf[0] * alrs[base] + xf[1] * alrs[base + 1] +
             xf[2] * alrs[base + 2] + xf[3] * alrs[base + 3];
    pr[hh] = xf[0] * alrs[1024 + base] + xf[1] * alrs[1024 + base + 1] +
             xf[2] * alrs[1024 + base + 2] + xf[3] * alrs[1024 + base + 3];
  }
  for (int off = 32; off; off >>= 1) {
#pragma unroll
    for (int hh = 0; hh < 4; ++hh) {
      pl[hh] += __shfl_xor(pl[hh], off);
      pr[hh] += __shfl_xor(pr[hh], off);
    }
  }
  if (lane == 0) {
#pragma unroll
    for (int hh = 0; hh < 4; ++hh) {
      el[n * HEADS + hh] = pl[hh];
      er[n * HEADS + hh] = pr[hh];
    }
  }
}

// ---------------- per-column softmax + weighted bf16 feature gather ----------
// Block = 4 (column, dim-half) tasks of 64 lanes each; half = blockIdx&1,
// which matches XCD parity under round-robin dispatch -> each XCD's L2 only
// caches one 4MB half of featb. Softmax redundant per half (identical).
__global__ __launch_bounds__(256) void agg_kernel(const int* __restrict__ colcnt,
                                                  const int* __restrict__ colsrc,
                                                  const float* __restrict__ el,
                                                  const float* __restrict__ er,
                                                  const bf16* __restrict__ featb,
                                                  const float* __restrict__ bias,
                                                  float* __restrict__ out) {
  __shared__ int tmp[4][CAPC];
  __shared__ int slist[4][CAPC];
  __shared__ float pbuf[4][2][CAPC];
  const int t = threadIdx.x;
  const int grp = t >> 6;   // 4 tasks per block
  const int lane = t & 63;  // lane within task
  const int hf = blockIdx.x & 1;              // dim-half (XCD parity)
  const int d = (blockIdx.x >> 1) * 4 + grp;  // destination column
  const int C = min(colcnt[d], CAPC);
  for (int i = lane; i < C; i += 64) tmp[grp][i] = colsrc[(size_t)d * CAPC + i];
  __syncthreads();
  // rank-sort ascending (unique ids -> bijective, deterministic vs atomics)
  for (int i = lane; i < C; i += 64) {
    const int v = tmp[grp][i];
    int rk = 0;
    for (int j = 0; j < C; ++j) rk += (tmp[grp][j] < v);
    slist[grp][rk] = v;
  }
  __syncthreads();
  const int sl = lane >> 5;   // sub-head within half
  const int h = hf * 2 + sl;  // global head
  const int hl = lane & 31;
  const float er_dh = er[d * HEADS + h];
  // pass A: e values -> pbuf, running max (32-lane subgroup)
  float m = -INFINITY;
  for (int i = hl; i < C; i += 32) {
    float e = el[slist[grp][i] * HEADS + h] + er_dh;
    e = e >= 0.f ? e : 0.2f * e;
    pbuf[grp][sl][i] = e;
    m = fmaxf(m, e);
  }
#pragma unroll
  for (int off = 16; off; off >>= 1) m = fmaxf(m, __shfl_xor(m, off));
  // pass B: exp in place, denom reduce
  float dsum = 0.f;
  for (int i = hl; i < C; i += 32) {
    const float p = __expf(pbuf[grp][sl][i] - m);
    pbuf[grp][sl][i] = p;
    dsum += p;
  }
#pragma unroll
  for (int off = 16; off; off >>= 1) dsum += __shfl_xor(dsum, off);
  __syncthreads();
  // pass C: weighted gather; 64 lanes x 16B = 1KB per (row, half)
  const size_t dimoff = hf * 512 + lane * 8;
  float acc[8] = {};
  int i = 0;
  for (; i + 2 <= C; i += 2) {
    const float p0 = pbuf[grp][sl][i];
    const float p1 = pbuf[grp][sl][i + 1];
    const uint4 v0 = *reinterpret_cast<const uint4*>(
        &featb[(size_t)slist[grp][i] * FOUT + dimoff]);
    const uint4 v1 = *reinterpret_cast<const uint4*>(
        &featb[(size_t)slist[grp][i + 1] * FOUT + dimoff]);
    acc[0] = fmaf(p0, bflo(v0.x), acc[0]);
    acc[1] = fmaf(p0, bfhi(v0.x), acc[1]);
    acc[2] = fmaf(p0, bflo(v0.y), acc[2]);
    acc[3] = fmaf(p0, bfhi(v0.y), acc[3]);
    acc[4] = fmaf(p0, bflo(v0.z), acc[4]);
    acc[5] = fmaf(p0, bfhi(v0.z), acc[5]);
    acc[6] = fmaf(p0, bflo(v0.w), acc[6]);
    acc[7] = fmaf(p0, bfhi(v0.w), acc[7]);
    acc[0] = fmaf(p1, bflo(v1.x), acc[0]);
    acc[1] = fmaf(p1, bfhi(v1.x), acc[1]);
    acc[2] = fmaf(p1, bflo(v1.y), acc[2]);
    acc[3] = fmaf(p1, bfhi(v1.y), acc[3]);
    acc[4] = fmaf(p1, bflo(v1.z), acc[4]);
    acc[5] = fmaf(p1, bfhi(v1.z), acc[5]);
    acc[6] = fmaf(p1, bflo(v1.w), acc[6]);
    acc[7] = fmaf(p1, bfhi(v1.w), acc[7]);
  }
  if (i < C) {
    const float p0 = pbuf[grp][sl][i];
    const uint4 v0 = *reinterpret_cast<const uint4*>(
        &featb[(size_t)slist[grp][i] * FOUT + dimoff]);
    acc[0] = fmaf(p0, bflo(v0.x), acc[0]);
    acc[1] = fmaf(p0, bfhi(v0.x), acc[1]);
    acc[2] = fmaf(p0, bflo(v0.y), acc[2]);
    acc[3] = fmaf(p0, bfhi(v0.y), acc[3]);
    acc[4] = fmaf(p0, bflo(v0.z), acc[4]);
    acc[5] = fmaf(p0, bfhi(v0.z), acc[5]);
    acc[6] = fmaf(p0, bflo(v0.w), acc[6]);
    acc[7] = fmaf(p0, bfhi(v0.w), acc[7]);
  }
  const float inv = C > 0 ? 1.f / dsum : 0.f;
  float o[8];
#pragma unroll
  for (int k = 0; k < 8; ++k) {
    const float r = acc[k] * inv + bias[dimoff + k];
    o[k] = r > 0.f ? r : expm1f(r);
  }
  float* op = &out[(size_t)d * FOUT + dimoff];
  *reinterpret_cast<float4*>(op) = make_float4(o[0], o[1], o[2], o[3]);
  *reinterpret_cast<float4*>(op + 4) = make_float4(o[4], o[5], o[6], o[7]);
}

extern "C" void kernel_launch(void* const* d_in, const int* in_sizes, int n_in,
                              void* d_out, int out_size, void* d_ws, size_t ws_size,
                              hipStream_t stream) {
  const float* h        = (const float*)d_in[0];
  const float* simlar   = (const float*)d_in[1];
  const float* adj      = (const float*)d_in[2];
  const float* W_trans  = (const float*)d_in[3];
  const float* gat_W    = (const float*)d_in[4];
  const float* attn_l   = (const float*)d_in[5];
  const float* attn_r   = (const float*)d_in[6];
  const float* gat_bias = (const float*)d_in[7];
  // sem_W1 / sem_b1 / sem_W2 unused: beta = softmax over singleton == 1 -> out == sem.
  float* out = (float*)d_out;

  char* ws = (char*)d_ws;
  const size_t MB = 1 << 20;
  bf16* hb    = (bf16*)(ws);                        // 4 MB   (N x FIN)
  bf16* Wtb   = (bf16*)(ws + 4 * MB);               // 256 KB (HID x FIN)
  bf16* gWtb  = (bf16*)(ws + 4 * MB + 512 * 1024);  // 512 KB (FOUT x HID)
  bf16* xb    = (bf16*)(ws + 5 * MB);               // 2 MB   (N x HID)
  float* el   = (float*)(ws + 7 * MB);              // 64 KB
  float* er   = (float*)(ws + 7 * MB + 65536);      // 64 KB
  float* alr2 = (float*)(ws + 7 * MB + 131072);     // 8 KB (al2 | ar2)
  bf16* featb = (bf16*)(ws + 8 * MB);               // 8 MB   (N x FOUT bf16)
  int* colcnt = (int*)(ws + 16 * MB);               // 16 KB
  int* colsrc = (int*)(ws + 17 * MB);               // 1.5 MB

  init_kernel<<<128, 256, 0, stream>>>(gat_W, attn_l, attn_r, alr2, colcnt);
  scan_kernel<<<N, 256, 0, stream>>>(h, W_trans, gat_W, adj, simlar,
                                     hb, Wtb, gWtb, colcnt, colsrc);
  gemm_mfma64<<<dim3(N / 64, HID / 64), 256, 0, stream>>>(hb, Wtb, xb, N, HID, FIN);
  gemm_mfma128<<<dim3(N / 128, FOUT / 128), 256, 0, stream>>>(xb, gWtb, featb, N, FOUT, HID);
  elr2_kernel<<<N / 4, 256, 0, stream>>>(xb, alr2, el, er);
  agg_kernel<<<N / 2, 256, 0, stream>>>(colcnt, colsrc, el, er, featb, gat_bias, out);
}

// Round 10
// 75.457 us; speedup vs baseline: 1.1230x; 1.0138x over previous
//
#include <hip/hip_runtime.h>
#include <hip/hip_bf16.h>
#include <math.h>

#define N 4096
#define FIN 512
#define HID 256
#define HEADS 4
#define DHEAD 256
#define FOUT 1024
#define TOPK 29
#define CAP 64    // per-row candidate capacity (mean ~20.5, sd ~4.5)
#define CAPC 96   // per-column source capacity (in-degree mean ~20.4)

typedef __attribute__((ext_vector_type(8))) short short8;
typedef __attribute__((ext_vector_type(4))) float f32x4;
typedef __hip_bfloat16 bf16;

__device__ __forceinline__ float bflo(unsigned int u) {
  return __uint_as_float(u << 16);
}
__device__ __forceinline__ float bfhi(unsigned int u) {
  return __uint_as_float(u & 0xffff0000u);
}

// ---- prep: colcnt zero + bf16 converts (coalesced reads) + alr2 projection --
// Linear work-item space; all segment boundaries are 64-aligned so the
// 16-lane alr2 shuffle groups are wave-contiguous and fully active.
//   seg0 [0, 4096):          colcnt[i] = 0
//   seg1 [+524288):          h float4 -> hb bf16x4
//   seg2 [+32768):           W_trans float4 (natural) -> Wtb^T scattered
//   seg3 [+65536):           gat_W float4 (natural) -> gWtb^T scattered
//   seg4 [+32768):           alr2 (16 lanes per output, shuffle reduce)
__global__ __launch_bounds__(256) void prep_kernel(
    const float* __restrict__ h, const float* __restrict__ W_trans,
    const float* __restrict__ gat_W, const float* __restrict__ attn_l,
    const float* __restrict__ attn_r, bf16* __restrict__ hb,
    bf16* __restrict__ Wtb, bf16* __restrict__ gWtb,
    float* __restrict__ alr2, int* __restrict__ colcnt) {
  const int S1 = 4096;
  const int S2 = S1 + N * FIN / 4;       // 528384
  const int S3 = S2 + HID * FIN / 4;     // 561152
  const int S4 = S3 + FOUT * HID / 4;    // 626688
  const int TOT = S4 + 2 * HEADS * HID * 16;  // 659456
  const int stride = gridDim.x * 256;
  for (int i = blockIdx.x * 256 + threadIdx.x; i < TOT; i += stride) {
    if (i < S1) {
      colcnt[i] = 0;
    } else if (i < S2) {
      const int j = i - S1;
      const float4 v = reinterpret_cast<const float4*>(h)[j];
      bf16 tmp[4];
      tmp[0] = __float2bfloat16(v.x);
      tmp[1] = __float2bfloat16(v.y);
      tmp[2] = __float2bfloat16(v.z);
      tmp[3] = __float2bfloat16(v.w);
      *reinterpret_cast<ushort4*>(&hb[(size_t)j * 4]) =
          *reinterpret_cast<ushort4*>(tmp);
    } else if (i < S3) {
      // W_trans [FIN][HID] natural float4 read -> Wtb [HID][FIN] scattered
      const int j4 = i - S2;
      const float4 v = reinterpret_cast<const float4*>(W_trans)[j4];
      const int k = j4 >> 6;          // fin row 0..511
      const int c0 = (j4 & 63) * 4;   // hid col 0..255
      Wtb[(size_t)(c0 + 0) * FIN + k] = __float2bfloat16(v.x);
      Wtb[(size_t)(c0 + 1) * FIN + k] = __float2bfloat16(v.y);
      Wtb[(size_t)(c0 + 2) * FIN + k] = __float2bfloat16(v.z);
      Wtb[(size_t)(c0 + 3) * FIN + k] = __float2bfloat16(v.w);
    } else if (i < S4) {
      // gat_W [HID][FOUT] natural float4 read -> gWtb [FOUT][HID] scattered
      const int j4 = i - S3;
      const float4 v = reinterpret_cast<const float4*>(gat_W)[j4];
      const int k = j4 >> 8;          // hid row 0..255
      const int c0 = (j4 & 255) * 4;  // fout col 0..1023
      gWtb[(size_t)(c0 + 0) * HID + k] = __float2bfloat16(v.x);
      gWtb[(size_t)(c0 + 1) * HID + k] = __float2bfloat16(v.y);
      gWtb[(size_t)(c0 + 2) * HID + k] = __float2bfloat16(v.z);
      gWtb[(size_t)(c0 + 3) * HID + k] = __float2bfloat16(v.w);
    } else {
      // alr2[j]: j<1024 -> al2[h][k]; else ar2[h][k]
      const int u = i - S4;
      const int j = u >> 4, l16 = u & 15;
      const float* vec = (j < 1024) ? attn_l : attn_r;
      const int jj = j & 1023;
      const int hh = jj >> 8, k = jj & 255;
      const float4* wp = reinterpret_cast<const float4*>(
          &gat_W[(size_t)k * FOUT + hh * DHEAD + l16 * 16]);
      const float4* vp = reinterpret_cast<const float4*>(&vec[hh * DHEAD + l16 * 16]);
      float acc = 0.f;
#pragma unroll
      for (int q = 0; q < 4; ++q) {
        const float4 w4 = wp[q], v4 = vp[q];
        acc += w4.x * v4.x + w4.y * v4.y + w4.z * v4.z + w4.w * v4.w;
      }
#pragma unroll
      for (int off = 1; off < 16; off <<= 1) acc += __shfl_xor(acc, off);
      if (l16 == 0) alr2[j] = acc;
    }
  }
}

// ---- pure row scan: 1 branch per 16 elements, LDS compact, rank top-29 -----
// adj values are exactly 0.0f or 1.0f -> integer OR of raw bits detects edges.
__global__ __launch_bounds__(256) void rowscan_kernel(const float* __restrict__ adj,
                                                      const float* __restrict__ simlar,
                                                      int* __restrict__ colcnt,
                                                      int* __restrict__ colsrc) {
  const int t = threadIdx.x, s = blockIdx.x;
  __shared__ float swv[CAP];
  __shared__ int swi[CAP];
  __shared__ int cnt;
  if (t == 0) cnt = 0;
  __syncthreads();
  const uint4* rowadj = reinterpret_cast<const uint4*>(adj + (size_t)s * N);
  const float4* rowsim = reinterpret_cast<const float4*>(simlar + (size_t)s * N);
  uint4 a[4];
#pragma unroll
  for (int q = 0; q < 4; ++q) a[q] = rowadj[q * 256 + t];  // 4 coalesced loads
  unsigned any = 0;
#pragma unroll
  for (int q = 0; q < 4; ++q) any |= a[q].x | a[q].y | a[q].z | a[q].w;
  if (any) {  // ~15% of threads
#pragma unroll
    for (int q = 0; q < 4; ++q) {
      if (a[q].x | a[q].y | a[q].z | a[q].w) {  // ~4% of sub-groups
        const int j = q * 256 + t;
        const float4 s4 = rowsim[j];
        const unsigned aw[4] = {a[q].x, a[q].y, a[q].z, a[q].w};
        const float ss[4] = {s4.x, s4.y, s4.z, s4.w};
#pragma unroll
        for (int c = 0; c < 4; ++c) {
          if (aw[c] && ss[c] > 0.f) {
            const int p = atomicAdd(&cnt, 1);
            if (p < CAP) {
              swv[p] = ss[c];
              swi[p] = j * 4 + c;
            }
          }
        }
      }
    }
  }
  __syncthreads();
  // rank select (value-based -> order-independent vs atomic arrival)
  const int C = min(cnt, CAP);
  if (t < C) {
    const float x = swv[t];
    int rk = 0;
    for (int jj = 0; jj < C; ++jj) rk += (swv[jj] > x);
    if (rk < TOPK) {
      const int d = swi[t];
      const int p = atomicAdd(&colcnt[d], 1);
      if (p < CAPC) colsrc[(size_t)d * CAPC + p] = s;
    }
  }
}

// ------- bf16 MFMA GEMM (64x64 tile, BK=64): xb = lrelu(hb @ Wtb^T) ---------
__global__ __launch_bounds__(256) void gemm_mfma64(const bf16* __restrict__ A,
                                                   const bf16* __restrict__ Bt,
                                                   bf16* __restrict__ Cb,
                                                   int M, int Nn, int K) {
  __shared__ bf16 As[64][72];  // +8 pad
  __shared__ bf16 Bs[64][72];
  const int t = threadIdx.x;
  const int bm = blockIdx.x * 64, bn = blockIdx.y * 64;
  const int w = t >> 6, lane = t & 63, r = lane & 15, g = lane >> 4;
  const int m = t >> 2, c0 = (t & 3) * 8;
  f32x4 acc[4] = {};
  for (int k0 = 0; k0 < K; k0 += 64) {
    const bf16* arow = &A[(size_t)(bm + m) * K + k0];
    const bf16* brow = &Bt[(size_t)(bn + m) * K + k0];
    *reinterpret_cast<int4*>(&As[m][c0]) = *reinterpret_cast<const int4*>(&arow[c0]);
    *reinterpret_cast<int4*>(&As[m][c0 + 32]) = *reinterpret_cast<const int4*>(&arow[c0 + 32]);
    *reinterpret_cast<int4*>(&Bs[m][c0]) = *reinterpret_cast<const int4*>(&brow[c0]);
    *reinterpret_cast<int4*>(&Bs[m][c0 + 32]) = *reinterpret_cast<const int4*>(&brow[c0 + 32]);
    __syncthreads();
    const short8 a0 = *reinterpret_cast<short8*>(&As[w * 16 + r][g * 8]);
    const short8 a1 = *reinterpret_cast<short8*>(&As[w * 16 + r][32 + g * 8]);
#pragma unroll
    for (int j = 0; j < 4; ++j) {
      const short8 b0 = *reinterpret_cast<short8*>(&Bs[j * 16 + r][g * 8]);
      const short8 b1 = *reinterpret_cast<short8*>(&Bs[j * 16 + r][32 + g * 8]);
      acc[j] = __builtin_amdgcn_mfma_f32_16x16x32_bf16(a0, b0, acc[j], 0, 0, 0);
      acc[j] = __builtin_amdgcn_mfma_f32_16x16x32_bf16(a1, b1, acc[j], 0, 0, 0);
    }
    __syncthreads();
  }
#pragma unroll
  for (int j = 0; j < 4; ++j)
#pragma unroll
    for (int q = 0; q < 4; ++q) {
      const int row = bm + w * 16 + g * 4 + q;
      const int col = bn + j * 16 + r;
      float v = acc[j][q];
      v = v >= 0.f ? v : 0.01f * v;  // lrelu(0.01)
      Cb[(size_t)row * Nn + col] = __float2bfloat16(v);
    }
}

// ------- bf16 MFMA GEMM (128x128 tile, BK=32): featb = xb @ gWtb^T ----------
__global__ __launch_bounds__(256) void gemm_mfma128(const bf16* __restrict__ A,
                                                    const bf16* __restrict__ Bt,
                                                    bf16* __restrict__ Cb,
                                                    int M, int Nn, int K) {
  __shared__ bf16 As[128][40];  // +8 pad
  __shared__ bf16 Bs[128][40];
  const int t = threadIdx.x;
  const int bm = blockIdx.x * 128, bn = blockIdx.y * 128;
  const int w = t >> 6, lane = t & 63, r = lane & 15, g = lane >> 4;
  const int m = t >> 1, c0 = (t & 1) * 16;
  f32x4 acc[2][8] = {};
  for (int k0 = 0; k0 < K; k0 += 32) {
    const bf16* arow = &A[(size_t)(bm + m) * K + k0 + c0];
    const bf16* brow = &Bt[(size_t)(bn + m) * K + k0 + c0];
    *reinterpret_cast<int4*>(&As[m][c0]) = *reinterpret_cast<const int4*>(arow);
    *reinterpret_cast<int4*>(&As[m][c0 + 8]) = *reinterpret_cast<const int4*>(arow + 8);
    *reinterpret_cast<int4*>(&Bs[m][c0]) = *reinterpret_cast<const int4*>(brow);
    *reinterpret_cast<int4*>(&Bs[m][c0 + 8]) = *reinterpret_cast<const int4*>(brow + 8);
    __syncthreads();
    const short8 a0 = *reinterpret_cast<short8*>(&As[w * 32 + r][g * 8]);
    const short8 a1 = *reinterpret_cast<short8*>(&As[w * 32 + 16 + r][g * 8]);
#pragma unroll
    for (int j = 0; j < 8; ++j) {
      const short8 b = *reinterpret_cast<short8*>(&Bs[j * 16 + r][g * 8]);
      acc[0][j] = __builtin_amdgcn_mfma_f32_16x16x32_bf16(a0, b, acc[0][j], 0, 0, 0);
      acc[1][j] = __builtin_amdgcn_mfma_f32_16x16x32_bf16(a1, b, acc[1][j], 0, 0, 0);
    }
    __syncthreads();
  }
#pragma unroll
  for (int i = 0; i < 2; ++i)
#pragma unroll
    for (int j = 0; j < 8; ++j)
#pragma unroll
      for (int q = 0; q < 4; ++q) {
        const int row = bm + w * 32 + i * 16 + g * 4 + q;
        const int col = bn + j * 16 + r;
        Cb[(size_t)row * Nn + col] = __float2bfloat16(acc[i][j][q]);
      }
}

// ---- el/er from xb and projected attn vectors: el[n,h] = xb[n,:]·al2[h,:] --
__global__ __launch_bounds__(256) void elr2_kernel(const bf16* __restrict__ xb,
                                                   const float* __restrict__ alr2,
                                                   float* __restrict__ el,
                                                   float* __restrict__ er) {
  __shared__ float alrs[2048];
  const int t = threadIdx.x;
  for (int i = t; i < 2048; i += 256) alrs[i] = alr2[i];
  __syncthreads();
  const int wv = t >> 6, lane = t & 63;
  const int n = blockIdx.x * 4 + wv;
  const uint2 v2 = *reinterpret_cast<const uint2*>(&xb[(size_t)n * HID + lane * 4]);
  const float xf[4] = {bflo(v2.x), bfhi(v2.x), bflo(v2.y), bfhi(v2.y)};
  float pl[4], pr[4];
#pragma unroll
  for (int hh = 0; hh < 4; ++hh) {
    const int base = hh * 256 + lane * 4;
    pl[hh] = xf[0] * alrs[base] + xf[1] * alrs[base + 1] +
             xf[2] * alrs[base + 2] + xf[3] * alrs[base + 3];
    pr[hh] = xf[0] * alrs[1024 + base] + xf[1] * alrs[1024 + base + 1] +
             xf[2] * alrs[1024 + base + 2] + xf[3] * alrs[1024 + base + 3];
  }
  for (int off = 32; off; off >>= 1) {
#pragma unroll
    for (int hh = 0; hh < 4; ++hh) {
      pl[hh] += __shfl_xor(pl[hh], off);
      pr[hh] += __shfl_xor(pr[hh], off);
    }
  }
  if (lane == 0) {
#pragma unroll
    for (int hh = 0; hh < 4; ++hh) {
      el[n * HEADS + hh] = pl[hh];
      er[n * HEADS + hh] = pr[hh];
    }
  }
}

// ---------------- per-column softmax + weighted bf16 feature gather ----------
// Block = 4 (column, dim-half) tasks; half = blockIdx&1 (XCD parity) so each
// XCD's L2 caches only one 4MB half of featb. Softmax redundant per half.
__global__ __launch_bounds__(256) void agg_kernel(const int* __restrict__ colcnt,
                                                  const int* __restrict__ colsrc,
                                                  const float* __restrict__ el,
                                                  const float* __restrict__ er,
                                                  const bf16* __restrict__ featb,
                                                  const float* __restrict__ bias,
                                                  float* __restrict__ out) {
  __shared__ int tmp[4][CAPC];
  __shared__ int slist[4][CAPC];
  __shared__ float pbuf[4][2][CAPC];
  const int t = threadIdx.x;
  const int grp = t >> 6;
  const int lane = t & 63;
  const int hf = blockIdx.x & 1;
  const int d = (blockIdx.x >> 1) * 4 + grp;
  const int C = min(colcnt[d], CAPC);
  for (int i = lane; i < C; i += 64) tmp[grp][i] = colsrc[(size_t)d * CAPC + i];
  __syncthreads();
  for (int i = lane; i < C; i += 64) {
    const int v = tmp[grp][i];
    int rk = 0;
    for (int j = 0; j < C; ++j) rk += (tmp[grp][j] < v);
    slist[grp][rk] = v;
  }
  __syncthreads();
  const int sl = lane >> 5;
  const int h = hf * 2 + sl;
  const int hl = lane & 31;
  const float er_dh = er[d * HEADS + h];
  float m = -INFINITY;
  for (int i = hl; i < C; i += 32) {
    float e = el[slist[grp][i] * HEADS + h] + er_dh;
    e = e >= 0.f ? e : 0.2f * e;
    pbuf[grp][sl][i] = e;
    m = fmaxf(m, e);
  }
#pragma unroll
  for (int off = 16; off; off >>= 1) m = fmaxf(m, __shfl_xor(m, off));
  float dsum = 0.f;
  for (int i = hl; i < C; i += 32) {
    const float p = __expf(pbuf[grp][sl][i] - m);
    pbuf[grp][sl][i] = p;
    dsum += p;
  }
#pragma unroll
  for (int off = 16; off; off >>= 1) dsum += __shfl_xor(dsum, off);
  __syncthreads();
  const size_t dimoff = hf * 512 + lane * 8;
  float acc[8] = {};
  int i = 0;
  for (; i + 2 <= C; i += 2) {
    const float p0 = pbuf[grp][sl][i];
    const float p1 = pbuf[grp][sl][i + 1];
    const uint4 v0 = *reinterpret_cast<const uint4*>(
        &featb[(size_t)slist[grp][i] * FOUT + dimoff]);
    const uint4 v1 = *reinterpret_cast<const uint4*>(
        &featb[(size_t)slist[grp][i + 1] * FOUT + dimoff]);
    acc[0] = fmaf(p0, bflo(v0.x), acc[0]);
    acc[1] = fmaf(p0, bfhi(v0.x), acc[1]);
    acc[2] = fmaf(p0, bflo(v0.y), acc[2]);
    acc[3] = fmaf(p0, bfhi(v0.y), acc[3]);
    acc[4] = fmaf(p0, bflo(v0.z), acc[4]);
    acc[5] = fmaf(p0, bfhi(v0.z), acc[5]);
    acc[6] = fmaf(p0, bflo(v0.w), acc[6]);
    acc[7] = fmaf(p0, bfhi(v0.w), acc[7]);
    acc[0] = fmaf(p1, bflo(v1.x), acc[0]);
    acc[1] = fmaf(p1, bfhi(v1.x), acc[1]);
    acc[2] = fmaf(p1, bflo(v1.y), acc[2]);
    acc[3] = fmaf(p1, bfhi(v1.y), acc[3]);
    acc[4] = fmaf(p1, bflo(v1.z), acc[4]);
    acc[5] = fmaf(p1, bfhi(v1.z), acc[5]);
    acc[6] = fmaf(p1, bflo(v1.w), acc[6]);
    acc[7] = fmaf(p1, bfhi(v1.w), acc[7]);
  }
  if (i < C) {
    const float p0 = pbuf[grp][sl][i];
    const uint4 v0 = *reinterpret_cast<const uint4*>(
        &featb[(size_t)slist[grp][i] * FOUT + dimoff]);
    acc[0] = fmaf(p0, bflo(v0.x), acc[0]);
    acc[1] = fmaf(p0, bfhi(v0.x), acc[1]);
    acc[2] = fmaf(p0, bflo(v0.y), acc[2]);
    acc[3] = fmaf(p0, bfhi(v0.y), acc[3]);
    acc[4] = fmaf(p0, bflo(v0.z), acc[4]);
    acc[5] = fmaf(p0, bfhi(v0.z), acc[5]);
    acc[6] = fmaf(p0, bflo(v0.w), acc[6]);
    acc[7] = fmaf(p0, bfhi(v0.w), acc[7]);
  }
  const float inv = C > 0 ? 1.f / dsum : 0.f;
  float o[8];
#pragma unroll
  for (int k = 0; k < 8; ++k) {
    const float r = acc[k] * inv + bias[dimoff + k];
    o[k] = r > 0.f ? r : expm1f(r);
  }
  float* op = &out[(size_t)d * FOUT + dimoff];
  *reinterpret_cast<float4*>(op) = make_float4(o[0], o[1], o[2], o[3]);
  *reinterpret_cast<float4*>(op + 4) = make_float4(o[4], o[5], o[6], o[7]);
}

extern "C" void kernel_launch(void* const* d_in, const int* in_sizes, int n_in,
                              void* d_out, int out_size, void* d_ws, size_t ws_size,
                              hipStream_t stream) {
  const float* h        = (const float*)d_in[0];
  const float* simlar   = (const float*)d_in[1];
  const float* adj      = (const float*)d_in[2];
  const float* W_trans  = (const float*)d_in[3];
  const float* gat_W    = (const float*)d_in[4];
  const float* attn_l   = (const float*)d_in[5];
  const float* attn_r   = (const float*)d_in[6];
  const float* gat_bias = (const float*)d_in[7];
  // sem_W1 / sem_b1 / sem_W2 unused: beta = softmax over singleton == 1 -> out == sem.
  float* out = (float*)d_out;

  char* ws = (char*)d_ws;
  const size_t MB = 1 << 20;
  bf16* hb    = (bf16*)(ws);                        // 4 MB   (N x FIN)
  bf16* Wtb   = (bf16*)(ws + 4 * MB);               // 256 KB (HID x FIN)
  bf16* gWtb  = (bf16*)(ws + 4 * MB + 512 * 1024);  // 512 KB (FOUT x HID)
  bf16* xb    = (bf16*)(ws + 5 * MB);               // 2 MB   (N x HID)
  float* el   = (float*)(ws + 7 * MB);              // 64 KB
  float* er   = (float*)(ws + 7 * MB + 65536);      // 64 KB
  float* alr2 = (float*)(ws + 7 * MB + 131072);     // 8 KB (al2 | ar2)
  bf16* featb = (bf16*)(ws + 8 * MB);               // 8 MB   (N x FOUT bf16)
  int* colcnt = (int*)(ws + 16 * MB);               // 16 KB
  int* colsrc = (int*)(ws + 17 * MB);               // 1.5 MB

  prep_kernel<<<2048, 256, 0, stream>>>(h, W_trans, gat_W, attn_l, attn_r,
                                        hb, Wtb, gWtb, alr2, colcnt);
  rowscan_kernel<<<N, 256, 0, stream>>>(adj, simlar, colcnt, colsrc);
  gemm_mfma64<<<dim3(N / 64, HID / 64), 256, 0, stream>>>(hb, Wtb, xb, N, HID, FIN);
  gemm_mfma128<<<dim3(N / 128, FOUT / 128), 256, 0, stream>>>(xb, gWtb, featb, N, FOUT, HID);
  elr2_kernel<<<N / 4, 256, 0, stream>>>(xb, alr2, el, er);
  agg_kernel<<<N / 2, 256, 0, stream>>>(colcnt, colsrc, el, er, featb, gat_bias, out);
}

// Round 11
// 67.111 us; speedup vs baseline: 1.2627x; 1.1244x over previous
//
#include <hip/hip_runtime.h>
#include <hip/hip_bf16.h>
#include <math.h>

#define N 4096
#define FIN 512
#define HID 256
#define HEADS 4
#define DHEAD 256
#define FOUT 1024
#define TOPK 29
#define CAP 64    // per-row candidate capacity (mean ~20.5, sd ~4.5)
#define CAPC 96   // per-column source capacity (in-degree mean ~20.4)

typedef __attribute__((ext_vector_type(8))) short short8;
typedef __attribute__((ext_vector_type(4))) float f32x4;
typedef __hip_bfloat16 bf16;

__device__ __forceinline__ float bflo(unsigned int u) {
  return __uint_as_float(u << 16);
}
__device__ __forceinline__ float bfhi(unsigned int u) {
  return __uint_as_float(u & 0xffff0000u);
}

// ---- scan: phase0 prep (tiny, coalesced) + block-per-row scan + top-29 -----
// phase0 segments (all 64-aligned; one item per thread at 4096 blocks):
//   [0,4096)        colcnt zero
//   [+32768)        W_trans [512][256] f32 natural read -> Wtb [256][512] bf16
//   [+65536)        gat_W  [256][1024] f32 natural read -> gWtb [1024][256] bf16
//   [+32768)        alr2 projection (16 lanes/output, shuffle reduce)
__global__ __launch_bounds__(256) void scan_kernel(
    const float* __restrict__ W_trans, const float* __restrict__ gat_W,
    const float* __restrict__ attn_l, const float* __restrict__ attn_r,
    const float* __restrict__ adj, const float* __restrict__ simlar,
    bf16* __restrict__ Wtb, bf16* __restrict__ gWtb,
    float* __restrict__ alr2, int* __restrict__ colcnt,
    int* __restrict__ colsrc) {
  const int t = threadIdx.x, s = blockIdx.x;
  // ---- phase 0 ----
  {
    const int S1 = 4096;
    const int S2 = S1 + HID * FIN / 4;        // 36864
    const int S3 = S2 + FOUT * HID / 4;       // 102400
    const int TOT = S3 + 2 * HEADS * HID * 16;  // 135168
    const int i = s * 256 + t;  // grid covers 1M slots > TOT: single pass
    if (i < TOT) {
      if (i < S1) {
        colcnt[i] = 0;
      } else if (i < S2) {
        const int j4 = i - S1;
        const float4 v = reinterpret_cast<const float4*>(W_trans)[j4];
        const int k = j4 >> 6;          // fin row 0..511
        const int c0 = (j4 & 63) * 4;   // hid col 0..255
        Wtb[(size_t)(c0 + 0) * FIN + k] = __float2bfloat16(v.x);
        Wtb[(size_t)(c0 + 1) * FIN + k] = __float2bfloat16(v.y);
        Wtb[(size_t)(c0 + 2) * FIN + k] = __float2bfloat16(v.z);
        Wtb[(size_t)(c0 + 3) * FIN + k] = __float2bfloat16(v.w);
      } else if (i < S3) {
        const int j4 = i - S2;
        const float4 v = reinterpret_cast<const float4*>(gat_W)[j4];
        const int k = j4 >> 8;          // hid row 0..255
        const int c0 = (j4 & 255) * 4;  // fout col 0..1023
        gWtb[(size_t)(c0 + 0) * HID + k] = __float2bfloat16(v.x);
        gWtb[(size_t)(c0 + 1) * HID + k] = __float2bfloat16(v.y);
        gWtb[(size_t)(c0 + 2) * HID + k] = __float2bfloat16(v.z);
        gWtb[(size_t)(c0 + 3) * HID + k] = __float2bfloat16(v.w);
      } else {
        const int u = i - S3;
        const int j = u >> 4, l16 = u & 15;
        const float* vec = (j < 1024) ? attn_l : attn_r;
        const int jj = j & 1023;
        const int hh = jj >> 8, k = jj & 255;
        const float4* wp = reinterpret_cast<const float4*>(
            &gat_W[(size_t)k * FOUT + hh * DHEAD + l16 * 16]);
        const float4* vp = reinterpret_cast<const float4*>(&vec[hh * DHEAD + l16 * 16]);
        float acc = 0.f;
#pragma unroll
        for (int q = 0; q < 4; ++q) {
          const float4 w4 = wp[q], v4 = vp[q];
          acc += w4.x * v4.x + w4.y * v4.y + w4.z * v4.z + w4.w * v4.w;
        }
#pragma unroll
        for (int off = 1; off < 16; off <<= 1) acc += __shfl_xor(acc, off);
        if (l16 == 0) alr2[j] = acc;
      }
    }
  }
  // ---- phase 1: scan row s (adj bits OR-detected; 1 branch / 16 elems) ----
  __shared__ float swv[CAP];
  __shared__ int swi[CAP];
  __shared__ int cnt;
  if (t == 0) cnt = 0;
  __syncthreads();
  const uint4* rowadj = reinterpret_cast<const uint4*>(adj + (size_t)s * N);
  const float4* rowsim = reinterpret_cast<const float4*>(simlar + (size_t)s * N);
  uint4 a[4];
#pragma unroll
  for (int q = 0; q < 4; ++q) a[q] = rowadj[q * 256 + t];
  unsigned any = 0;
#pragma unroll
  for (int q = 0; q < 4; ++q) any |= a[q].x | a[q].y | a[q].z | a[q].w;
  if (any) {
#pragma unroll
    for (int q = 0; q < 4; ++q) {
      if (a[q].x | a[q].y | a[q].z | a[q].w) {
        const int j = q * 256 + t;
        const float4 s4 = rowsim[j];
        const unsigned aw[4] = {a[q].x, a[q].y, a[q].z, a[q].w};
        const float ss[4] = {s4.x, s4.y, s4.z, s4.w};
#pragma unroll
        for (int c = 0; c < 4; ++c) {
          if (aw[c] && ss[c] > 0.f) {
            const int p = atomicAdd(&cnt, 1);
            if (p < CAP) {
              swv[p] = ss[c];
              swi[p] = j * 4 + c;
            }
          }
        }
      }
    }
  }
  __syncthreads();
  // ---- phase 2: rank select (value-based, order-independent) ----
  const int C = min(cnt, CAP);
  if (t < C) {
    const float x = swv[t];
    int rk = 0;
    for (int jj = 0; jj < C; ++jj) rk += (swv[jj] > x);
    if (rk < TOPK) {
      const int d = swi[t];
      const int p = atomicAdd(&colcnt[d], 1);
      if (p < CAPC) colsrc[(size_t)d * CAPC + p] = s;
    }
  }
}

// ------- GEMM1 (64x64, BK=64): xb = lrelu(h_f32 @ Wtb^T), cvt in staging ----
__global__ __launch_bounds__(256) void gemm_h(const float* __restrict__ A,
                                              const bf16* __restrict__ Bt,
                                              bf16* __restrict__ Cb) {
  __shared__ bf16 As[64][72];  // +8 pad
  __shared__ bf16 Bs[64][72];
  const int t = threadIdx.x;
  const int bm = blockIdx.x * 64, bn = blockIdx.y * 64;
  const int w = t >> 6, lane = t & 63, r = lane & 15, g = lane >> 4;
  const int m = t >> 2;
  const int fb = (t & 3) * 16;  // 16 floats per thread per row-quarter
  const int c0 = (t & 3) * 8;   // B staging chunks
  f32x4 acc[4] = {};
  for (int k0 = 0; k0 < FIN; k0 += 64) {
    {  // A: fp32 -> bf16 convert into LDS
      const float4* hp = reinterpret_cast<const float4*>(&A[(size_t)(bm + m) * FIN + k0 + fb]);
      const float4 f0 = hp[0], f1 = hp[1], f2 = hp[2], f3 = hp[3];
      bf16 ta[16];
      ta[0] = __float2bfloat16(f0.x); ta[1] = __float2bfloat16(f0.y);
      ta[2] = __float2bfloat16(f0.z); ta[3] = __float2bfloat16(f0.w);
      ta[4] = __float2bfloat16(f1.x); ta[5] = __float2bfloat16(f1.y);
      ta[6] = __float2bfloat16(f1.z); ta[7] = __float2bfloat16(f1.w);
      ta[8] = __float2bfloat16(f2.x); ta[9] = __float2bfloat16(f2.y);
      ta[10] = __float2bfloat16(f2.z); ta[11] = __float2bfloat16(f2.w);
      ta[12] = __float2bfloat16(f3.x); ta[13] = __float2bfloat16(f3.y);
      ta[14] = __float2bfloat16(f3.z); ta[15] = __float2bfloat16(f3.w);
      *reinterpret_cast<int4*>(&As[m][fb]) = *reinterpret_cast<int4*>(&ta[0]);
      *reinterpret_cast<int4*>(&As[m][fb + 8]) = *reinterpret_cast<int4*>(&ta[8]);
    }
    {  // B: bf16 direct
      const bf16* brow = &Bt[(size_t)(bn + m) * FIN + k0];
      *reinterpret_cast<int4*>(&Bs[m][c0]) = *reinterpret_cast<const int4*>(&brow[c0]);
      *reinterpret_cast<int4*>(&Bs[m][c0 + 32]) = *reinterpret_cast<const int4*>(&brow[c0 + 32]);
    }
    __syncthreads();
    const short8 a0 = *reinterpret_cast<short8*>(&As[w * 16 + r][g * 8]);
    const short8 a1 = *reinterpret_cast<short8*>(&As[w * 16 + r][32 + g * 8]);
#pragma unroll
    for (int j = 0; j < 4; ++j) {
      const short8 b0 = *reinterpret_cast<short8*>(&Bs[j * 16 + r][g * 8]);
      const short8 b1 = *reinterpret_cast<short8*>(&Bs[j * 16 + r][32 + g * 8]);
      acc[j] = __builtin_amdgcn_mfma_f32_16x16x32_bf16(a0, b0, acc[j], 0, 0, 0);
      acc[j] = __builtin_amdgcn_mfma_f32_16x16x32_bf16(a1, b1, acc[j], 0, 0, 0);
    }
    __syncthreads();
  }
#pragma unroll
  for (int j = 0; j < 4; ++j)
#pragma unroll
    for (int q = 0; q < 4; ++q) {
      const int row = bm + w * 16 + g * 4 + q;
      const int col = bn + j * 16 + r;
      float v = acc[j][q];
      v = v >= 0.f ? v : 0.01f * v;  // lrelu(0.01)
      Cb[(size_t)row * HID + col] = __float2bfloat16(v);
    }
}

// ------- GEMM2 (128x128, BK=64): featb_hm[h][n][d] = (xb @ gWtb^T) ----------
// Output stored HEAD-MAJOR [4][N][256] so agg's per-head gather is L2-local.
__global__ __launch_bounds__(256) void gemm128(const bf16* __restrict__ A,
                                               const bf16* __restrict__ Bt,
                                               bf16* __restrict__ Cb) {
  __shared__ bf16 As[128][72];  // +8 pad
  __shared__ bf16 Bs[128][72];
  const int t = threadIdx.x;
  const int bm = blockIdx.x * 128, bn = blockIdx.y * 128;
  const int w = t >> 6, lane = t & 63, r = lane & 15, g = lane >> 4;
  const int m = t >> 1, cb = (t & 1) * 32;
  f32x4 acc[2][8] = {};
  for (int k0 = 0; k0 < HID; k0 += 64) {
    const bf16* arow = &A[(size_t)(bm + m) * HID + k0 + cb];
    const bf16* brow = &Bt[(size_t)(bn + m) * HID + k0 + cb];
#pragma unroll
    for (int q = 0; q < 4; ++q) {
      *reinterpret_cast<int4*>(&As[m][cb + q * 8]) =
          *reinterpret_cast<const int4*>(&arow[q * 8]);
      *reinterpret_cast<int4*>(&Bs[m][cb + q * 8]) =
          *reinterpret_cast<const int4*>(&brow[q * 8]);
    }
    __syncthreads();
    const short8 a00 = *reinterpret_cast<short8*>(&As[w * 32 + r][g * 8]);
    const short8 a01 = *reinterpret_cast<short8*>(&As[w * 32 + r][32 + g * 8]);
    const short8 a10 = *reinterpret_cast<short8*>(&As[w * 32 + 16 + r][g * 8]);
    const short8 a11 = *reinterpret_cast<short8*>(&As[w * 32 + 16 + r][32 + g * 8]);
#pragma unroll
    for (int j = 0; j < 8; ++j) {
      const short8 b0 = *reinterpret_cast<short8*>(&Bs[j * 16 + r][g * 8]);
      const short8 b1 = *reinterpret_cast<short8*>(&Bs[j * 16 + r][32 + g * 8]);
      acc[0][j] = __builtin_amdgcn_mfma_f32_16x16x32_bf16(a00, b0, acc[0][j], 0, 0, 0);
      acc[0][j] = __builtin_amdgcn_mfma_f32_16x16x32_bf16(a01, b1, acc[0][j], 0, 0, 0);
      acc[1][j] = __builtin_amdgcn_mfma_f32_16x16x32_bf16(a10, b0, acc[1][j], 0, 0, 0);
      acc[1][j] = __builtin_amdgcn_mfma_f32_16x16x32_bf16(a11, b1, acc[1][j], 0, 0, 0);
    }
    __syncthreads();
  }
  const int hh = bn >> 8;          // head (constant per block; bn%128==0)
  const int dbase = bn & 255;      // dim offset within head
#pragma unroll
  for (int i = 0; i < 2; ++i)
#pragma unroll
    for (int j = 0; j < 8; ++j)
#pragma unroll
      for (int q = 0; q < 4; ++q) {
        const int row = bm + w * 32 + i * 16 + g * 4 + q;
        const int dd = dbase + j * 16 + r;
        Cb[((size_t)hh * N + row) * DHEAD + dd] = __float2bfloat16(acc[i][j][q]);
      }
}

// ---- el/er from xb and projected attn vectors: el[n,h] = xb[n,:]·al2[h,:] --
__global__ __launch_bounds__(256) void elr2_kernel(const bf16* __restrict__ xb,
                                                   const float* __restrict__ alr2,
                                                   float* __restrict__ el,
                                                   float* __restrict__ er) {
  __shared__ float alrs[2048];
  const int t = threadIdx.x;
  for (int i = t; i < 2048; i += 256) alrs[i] = alr2[i];
  __syncthreads();
  const int wv = t >> 6, lane = t & 63;
  const int n = blockIdx.x * 4 + wv;
  const uint2 v2 = *reinterpret_cast<const uint2*>(&xb[(size_t)n * HID + lane * 4]);
  const float xf[4] = {bflo(v2.x), bfhi(v2.x), bflo(v2.y), bfhi(v2.y)};
  float pl[4], pr[4];
#pragma unroll
  for (int hh = 0; hh < 4; ++hh) {
    const int base = hh * 256 + lane * 4;
    pl[hh] = xf[0] * alrs[base] + xf[1] * alrs[base + 1] +
             xf[2] * alrs[base + 2] + xf[3] * alrs[base + 3];
    pr[hh] = xf[0] * alrs[1024 + base] + xf[1] * alrs[1024 + base + 1] +
             xf[2] * alrs[1024 + base + 2] + xf[3] * alrs[1024 + base + 3];
  }
  for (int off = 32; off; off >>= 1) {
#pragma unroll
    for (int hh = 0; hh < 4; ++hh) {
      pl[hh] += __shfl_xor(pl[hh], off);
      pr[hh] += __shfl_xor(pr[hh], off);
    }
  }
  if (lane == 0) {
#pragma unroll
    for (int hh = 0; hh < 4; ++hh) {
      el[n * HEADS + hh] = pl[hh];
      er[n * HEADS + hh] = pr[hh];
    }
  }
}

// ---- agg: one WAVE per (column, head); head = blockIdx&3 -> XCD affinity ---
// featb head-major: each head's 2MB slab served by 2 XCDs' L2s. All LDS state
// is wave-private -> no block barriers at all.
__global__ __launch_bounds__(256) void agg_kernel(const int* __restrict__ colcnt,
                                                  const int* __restrict__ colsrc,
                                                  const float* __restrict__ el,
                                                  const float* __restrict__ er,
                                                  const bf16* __restrict__ featb,
                                                  const float* __restrict__ bias,
                                                  float* __restrict__ out) {
  __shared__ int tmp[4][CAPC];
  __shared__ int slist[4][CAPC];
  __shared__ float pbuf[4][CAPC];
  const int t = threadIdx.x;
  const int grp = t >> 6;   // wave id = column slot
  const int lane = t & 63;
  const int h = blockIdx.x & 3;                 // head (XCD-affine)
  const int d = (blockIdx.x >> 2) * 4 + grp;    // destination column
  const int C = min(colcnt[d], CAPC);
  for (int i = lane; i < C; i += 64) tmp[grp][i] = colsrc[(size_t)d * CAPC + i];
  // wave-private LDS: in-order within wave, no barriers needed
  for (int i = lane; i < C; i += 64) {
    const int v = tmp[grp][i];
    int rk = 0;
    for (int j = 0; j < C; ++j) rk += (tmp[grp][j] < v);
    slist[grp][rk] = v;
  }
  const float er_dh = er[d * HEADS + h];
  float m = -INFINITY;
  for (int i = lane; i < C; i += 64) {
    float e = el[slist[grp][i] * HEADS + h] + er_dh;
    e = e >= 0.f ? e : 0.2f * e;
    pbuf[grp][i] = e;
    m = fmaxf(m, e);
  }
#pragma unroll
  for (int off = 32; off; off >>= 1) m = fmaxf(m, __shfl_xor(m, off));
  float dsum = 0.f;
  for (int i = lane; i < C; i += 64) {
    const float p = __expf(pbuf[grp][i] - m);
    pbuf[grp][i] = p;
    dsum += p;
  }
#pragma unroll
  for (int off = 32; off; off >>= 1) dsum += __shfl_xor(dsum, off);
  // gather: 64 lanes x 8B (uint2 = 4 bf16) = 512B per source row
  const bf16* fh = featb + (size_t)h * N * DHEAD;
  float a0 = 0.f, a1 = 0.f, a2 = 0.f, a3 = 0.f;
  int i = 0;
  for (; i + 2 <= C; i += 2) {
    const float p0 = pbuf[grp][i];
    const float p1 = pbuf[grp][i + 1];
    const uint2 v0 = *reinterpret_cast<const uint2*>(
        &fh[(size_t)slist[grp][i] * DHEAD + lane * 4]);
    const uint2 v1 = *reinterpret_cast<const uint2*>(
        &fh[(size_t)slist[grp][i + 1] * DHEAD + lane * 4]);
    a0 = fmaf(p0, bflo(v0.x), a0);
    a1 = fmaf(p0, bfhi(v0.x), a1);
    a2 = fmaf(p0, bflo(v0.y), a2);
    a3 = fmaf(p0, bfhi(v0.y), a3);
    a0 = fmaf(p1, bflo(v1.x), a0);
    a1 = fmaf(p1, bfhi(v1.x), a1);
    a2 = fmaf(p1, bflo(v1.y), a2);
    a3 = fmaf(p1, bfhi(v1.y), a3);
  }
  if (i < C) {
    const float p0 = pbuf[grp][i];
    const uint2 v0 = *reinterpret_cast<const uint2*>(
        &fh[(size_t)slist[grp][i] * DHEAD + lane * 4]);
    a0 = fmaf(p0, bflo(v0.x), a0);
    a1 = fmaf(p0, bfhi(v0.x), a1);
    a2 = fmaf(p0, bflo(v0.y), a2);
    a3 = fmaf(p0, bfhi(v0.y), a3);
  }
  const float inv = C > 0 ? 1.f / dsum : 0.f;
  const int dbase = h * DHEAD + lane * 4;
  float o[4];
  o[0] = a0 * inv + bias[dbase + 0];
  o[1] = a1 * inv + bias[dbase + 1];
  o[2] = a2 * inv + bias[dbase + 2];
  o[3] = a3 * inv + bias[dbase + 3];
#pragma unroll
  for (int k = 0; k < 4; ++k) o[k] = o[k] > 0.f ? o[k] : expm1f(o[k]);
  *reinterpret_cast<float4*>(&out[(size_t)d * FOUT + dbase]) =
      make_float4(o[0], o[1], o[2], o[3]);
}

extern "C" void kernel_launch(void* const* d_in, const int* in_sizes, int n_in,
                              void* d_out, int out_size, void* d_ws, size_t ws_size,
                              hipStream_t stream) {
  const float* h        = (const float*)d_in[0];
  const float* simlar   = (const float*)d_in[1];
  const float* adj      = (const float*)d_in[2];
  const float* W_trans  = (const float*)d_in[3];
  const float* gat_W    = (const float*)d_in[4];
  const float* attn_l   = (const float*)d_in[5];
  const float* attn_r   = (const float*)d_in[6];
  const float* gat_bias = (const float*)d_in[7];
  // sem_W1 / sem_b1 / sem_W2 unused: beta = softmax over singleton == 1 -> out == sem.
  float* out = (float*)d_out;

  char* ws = (char*)d_ws;
  const size_t MB = 1 << 20;
  bf16* Wtb   = (bf16*)(ws);                    // 256 KB (HID x FIN)
  bf16* gWtb  = (bf16*)(ws + 512 * 1024);       // 512 KB (FOUT x HID)
  bf16* xb    = (bf16*)(ws + 1 * MB);           // 2 MB   (N x HID)
  float* el   = (float*)(ws + 3 * MB);          // 64 KB
  float* er   = (float*)(ws + 3 * MB + 65536);  // 64 KB
  float* alr2 = (float*)(ws + 3 * MB + 131072); // 8 KB
  bf16* featb = (bf16*)(ws + 4 * MB);           // 8 MB   [4][N][256] head-major
  int* colcnt = (int*)(ws + 12 * MB);           // 16 KB
  int* colsrc = (int*)(ws + 13 * MB);           // 1.5 MB

  scan_kernel<<<N, 256, 0, stream>>>(W_trans, gat_W, attn_l, attn_r, adj, simlar,
                                     Wtb, gWtb, alr2, colcnt, colsrc);
  gemm_h<<<dim3(N / 64, HID / 64), 256, 0, stream>>>(h, Wtb, xb);
  gemm128<<<dim3(N / 128, FOUT / 128), 256, 0, stream>>>(xb, gWtb, featb);
  elr2_kernel<<<N / 4, 256, 0, stream>>>(xb, alr2, el, er);
  agg_kernel<<<N, 256, 0, stream>>>(colcnt, colsrc, el, er, featb, gat_bias, out);
}

// Round 13
// 66.249 us; speedup vs baseline: 1.2791x; 1.0130x over previous
//
#include <hip/hip_runtime.h>
#include <hip/hip_bf16.h>
#include <math.h>

#define N 4096
#define FIN 512
#define HID 256
#define HEADS 4
#define DHEAD 256
#define FOUT 1024
#define TOPK 29
#define CAP 64    // per-row candidate capacity (mean ~20.5, sd ~4.5)
#define CAPC 96   // per-column source capacity (in-degree mean ~20.4)

typedef __attribute__((ext_vector_type(8))) short short8;
typedef __attribute__((ext_vector_type(4))) float f32x4;
typedef __hip_bfloat16 bf16;

__device__ __forceinline__ float bflo(unsigned int u) {
  return __uint_as_float(u << 16);
}
__device__ __forceinline__ float bfhi(unsigned int u) {
  return __uint_as_float(u & 0xffff0000u);
}

// ---- scan: phase0 prep (tiny, coalesced) + block-per-row scan + top-29 -----
__global__ __launch_bounds__(256) void scan_kernel(
    const float* __restrict__ W_trans, const float* __restrict__ gat_W,
    const float* __restrict__ attn_l, const float* __restrict__ attn_r,
    const float* __restrict__ adj, const float* __restrict__ simlar,
    bf16* __restrict__ Wtb, bf16* __restrict__ gWtb,
    float* __restrict__ alr2, int* __restrict__ colcnt,
    int* __restrict__ colsrc) {
  const int t = threadIdx.x, s = blockIdx.x;
  // ---- phase 0 ----
  {
    const int S1 = 4096;
    const int S2 = S1 + HID * FIN / 4;          // 36864
    const int S3 = S2 + FOUT * HID / 4;         // 102400
    const int TOT = S3 + 2 * HEADS * HID * 16;  // 135168
    const int i = s * 256 + t;  // grid covers 1M slots > TOT: single pass
    if (i < TOT) {
      if (i < S1) {
        colcnt[i] = 0;
      } else if (i < S2) {
        const int j4 = i - S1;
        const float4 v = reinterpret_cast<const float4*>(W_trans)[j4];
        const int k = j4 >> 6;          // fin row 0..511
        const int c0 = (j4 & 63) * 4;   // hid col 0..255
        Wtb[(size_t)(c0 + 0) * FIN + k] = __float2bfloat16(v.x);
        Wtb[(size_t)(c0 + 1) * FIN + k] = __float2bfloat16(v.y);
        Wtb[(size_t)(c0 + 2) * FIN + k] = __float2bfloat16(v.z);
        Wtb[(size_t)(c0 + 3) * FIN + k] = __float2bfloat16(v.w);
      } else if (i < S3) {
        const int j4 = i - S2;
        const float4 v = reinterpret_cast<const float4*>(gat_W)[j4];
        const int k = j4 >> 8;          // hid row 0..255
        const int c0 = (j4 & 255) * 4;  // fout col 0..1023
        gWtb[(size_t)(c0 + 0) * HID + k] = __float2bfloat16(v.x);
        gWtb[(size_t)(c0 + 1) * HID + k] = __float2bfloat16(v.y);
        gWtb[(size_t)(c0 + 2) * HID + k] = __float2bfloat16(v.z);
        gWtb[(size_t)(c0 + 3) * HID + k] = __float2bfloat16(v.w);
      } else {
        const int u = i - S3;
        const int j = u >> 4, l16 = u & 15;
        const float* vec = (j < 1024) ? attn_l : attn_r;
        const int jj = j & 1023;
        const int hh = jj >> 8, k = jj & 255;
        const float4* wp = reinterpret_cast<const float4*>(
            &gat_W[(size_t)k * FOUT + hh * DHEAD + l16 * 16]);
        const float4* vp = reinterpret_cast<const float4*>(&vec[hh * DHEAD + l16 * 16]);
        float acc = 0.f;
#pragma unroll
        for (int q = 0; q < 4; ++q) {
          const float4 w4 = wp[q], v4 = vp[q];
          acc += w4.x * v4.x + w4.y * v4.y + w4.z * v4.z + w4.w * v4.w;
        }
#pragma unroll
        for (int off = 1; off < 16; off <<= 1) acc += __shfl_xor(acc, off);
        if (l16 == 0) alr2[j] = acc;
      }
    }
  }
  // ---- phase 1: scan row s (adj bits OR-detected; 1 branch / 16 elems) ----
  __shared__ float swv[CAP];
  __shared__ int swi[CAP];
  __shared__ int cnt;
  if (t == 0) cnt = 0;
  __syncthreads();
  const uint4* rowadj = reinterpret_cast<const uint4*>(adj + (size_t)s * N);
  const float4* rowsim = reinterpret_cast<const float4*>(simlar + (size_t)s * N);
  uint4 a[4];
#pragma unroll
  for (int q = 0; q < 4; ++q) a[q] = rowadj[q * 256 + t];
  unsigned any = 0;
#pragma unroll
  for (int q = 0; q < 4; ++q) any |= a[q].x | a[q].y | a[q].z | a[q].w;
  if (any) {
#pragma unroll
    for (int q = 0; q < 4; ++q) {
      if (a[q].x | a[q].y | a[q].z | a[q].w) {
        const int j = q * 256 + t;
        const float4 s4 = rowsim[j];
        const unsigned aw[4] = {a[q].x, a[q].y, a[q].z, a[q].w};
        const float ss[4] = {s4.x, s4.y, s4.z, s4.w};
#pragma unroll
        for (int c = 0; c < 4; ++c) {
          if (aw[c] && ss[c] > 0.f) {
            const int p = atomicAdd(&cnt, 1);
            if (p < CAP) {
              swv[p] = ss[c];
              swi[p] = j * 4 + c;
            }
          }
        }
      }
    }
  }
  __syncthreads();
  // ---- phase 2: rank select (value-based, order-independent) ----
  const int C = min(cnt, CAP);
  if (t < C) {
    const float x = swv[t];
    int rk = 0;
    for (int jj = 0; jj < C; ++jj) rk += (swv[jj] > x);
    if (rk < TOPK) {
      const int d = swi[t];
      const int p = atomicAdd(&colcnt[d], 1);
      if (p < CAPC) colsrc[(size_t)d * CAPC + p] = s;
    }
  }
}

// ------- GEMM1 (64x64, BK=64): xb = lrelu(h_f32 @ Wtb^T), cvt in staging ----
__global__ __launch_bounds__(256) void gemm_h(const float* __restrict__ A,
                                              const bf16* __restrict__ Bt,
                                              bf16* __restrict__ Cb) {
  __shared__ bf16 As[64][72];  // +8 pad
  __shared__ bf16 Bs[64][72];
  const int t = threadIdx.x;
  const int bm = blockIdx.x * 64, bn = blockIdx.y * 64;
  const int w = t >> 6, lane = t & 63, r = lane & 15, g = lane >> 4;
  const int m = t >> 2;
  const int fb = (t & 3) * 16;  // 16 floats per thread per row-quarter
  const int c0 = (t & 3) * 8;   // B staging chunks
  f32x4 acc[4] = {};
  for (int k0 = 0; k0 < FIN; k0 += 64) {
    {  // A: fp32 -> bf16 convert into LDS
      const float4* hp = reinterpret_cast<const float4*>(&A[(size_t)(bm + m) * FIN + k0 + fb]);
      const float4 f0 = hp[0], f1 = hp[1], f2 = hp[2], f3 = hp[3];
      bf16 ta[16];
      ta[0] = __float2bfloat16(f0.x); ta[1] = __float2bfloat16(f0.y);
      ta[2] = __float2bfloat16(f0.z); ta[3] = __float2bfloat16(f0.w);
      ta[4] = __float2bfloat16(f1.x); ta[5] = __float2bfloat16(f1.y);
      ta[6] = __float2bfloat16(f1.z); ta[7] = __float2bfloat16(f1.w);
      ta[8] = __float2bfloat16(f2.x); ta[9] = __float2bfloat16(f2.y);
      ta[10] = __float2bfloat16(f2.z); ta[11] = __float2bfloat16(f2.w);
      ta[12] = __float2bfloat16(f3.x); ta[13] = __float2bfloat16(f3.y);
      ta[14] = __float2bfloat16(f3.z); ta[15] = __float2bfloat16(f3.w);
      *reinterpret_cast<int4*>(&As[m][fb]) = *reinterpret_cast<int4*>(&ta[0]);
      *reinterpret_cast<int4*>(&As[m][fb + 8]) = *reinterpret_cast<int4*>(&ta[8]);
    }
    {  // B: bf16 direct
      const bf16* brow = &Bt[(size_t)(bn + m) * FIN + k0];
      *reinterpret_cast<int4*>(&Bs[m][c0]) = *reinterpret_cast<const int4*>(&brow[c0]);
      *reinterpret_cast<int4*>(&Bs[m][c0 + 32]) = *reinterpret_cast<const int4*>(&brow[c0 + 32]);
    }
    __syncthreads();
    const short8 a0 = *reinterpret_cast<short8*>(&As[w * 16 + r][g * 8]);
    const short8 a1 = *reinterpret_cast<short8*>(&As[w * 16 + r][32 + g * 8]);
#pragma unroll
    for (int j = 0; j < 4; ++j) {
      const short8 b0 = *reinterpret_cast<short8*>(&Bs[j * 16 + r][g * 8]);
      const short8 b1 = *reinterpret_cast<short8*>(&Bs[j * 16 + r][32 + g * 8]);
      acc[j] = __builtin_amdgcn_mfma_f32_16x16x32_bf16(a0, b0, acc[j], 0, 0, 0);
      acc[j] = __builtin_amdgcn_mfma_f32_16x16x32_bf16(a1, b1, acc[j], 0, 0, 0);
    }
    __syncthreads();
  }
#pragma unroll
  for (int j = 0; j < 4; ++j)
#pragma unroll
    for (int q = 0; q < 4; ++q) {
      const int row = bm + w * 16 + g * 4 + q;
      const int col = bn + j * 16 + r;
      float v = acc[j][q];
      v = v >= 0.f ? v : 0.01f * v;  // lrelu(0.01)
      Cb[(size_t)row * HID + col] = __float2bfloat16(v);
    }
}

// ------- GEMM2 (128x128, BK=64): featb_hm[h][n][d] = (xb @ gWtb^T) ----------
// Output stored HEAD-MAJOR [4][N][256] so agg's per-head gather is L2-local.
__global__ __launch_bounds__(256) void gemm128(const bf16* __restrict__ A,
                                               const bf16* __restrict__ Bt,
                                               bf16* __restrict__ Cb) {
  __shared__ bf16 As[128][72];  // +8 pad
  __shared__ bf16 Bs[128][72];
  const int t = threadIdx.x;
  const int bm = blockIdx.x * 128, bn = blockIdx.y * 128;
  const int w = t >> 6, lane = t & 63, r = lane & 15, g = lane >> 4;
  const int m = t >> 1, cb = (t & 1) * 32;
  f32x4 acc[2][8] = {};
  for (int k0 = 0; k0 < HID; k0 += 64) {
    const bf16* arow = &A[(size_t)(bm + m) * HID + k0 + cb];
    const bf16* brow = &Bt[(size_t)(bn + m) * HID + k0 + cb];
#pragma unroll
    for (int q = 0; q < 4; ++q) {
      *reinterpret_cast<int4*>(&As[m][cb + q * 8]) =
          *reinterpret_cast<const int4*>(&arow[q * 8]);
      *reinterpret_cast<int4*>(&Bs[m][cb + q * 8]) =
          *reinterpret_cast<const int4*>(&brow[q * 8]);
    }
    __syncthreads();
    const short8 a00 = *reinterpret_cast<short8*>(&As[w * 32 + r][g * 8]);
    const short8 a01 = *reinterpret_cast<short8*>(&As[w * 32 + r][32 + g * 8]);
    const short8 a10 = *reinterpret_cast<short8*>(&As[w * 32 + 16 + r][g * 8]);
    const short8 a11 = *reinterpret_cast<short8*>(&As[w * 32 + 16 + r][32 + g * 8]);
#pragma unroll
    for (int j = 0; j < 8; ++j) {
      const short8 b0 = *reinterpret_cast<short8*>(&Bs[j * 16 + r][g * 8]);
      const short8 b1 = *reinterpret_cast<short8*>(&Bs[j * 16 + r][32 + g * 8]);
      acc[0][j] = __builtin_amdgcn_mfma_f32_16x16x32_bf16(a00, b0, acc[0][j], 0, 0, 0);
      acc[0][j] = __builtin_amdgcn_mfma_f32_16x16x32_bf16(a01, b1, acc[0][j], 0, 0, 0);
      acc[1][j] = __builtin_amdgcn_mfma_f32_16x16x32_bf16(a10, b0, acc[1][j], 0, 0, 0);
      acc[1][j] = __builtin_amdgcn_mfma_f32_16x16x32_bf16(a11, b1, acc[1][j], 0, 0, 0);
    }
    __syncthreads();
  }
  const int hh = bn >> 8;          // head (constant per block; bn%128==0)
  const int dbase = bn & 255;      // dim offset within head
#pragma unroll
  for (int i = 0; i < 2; ++i)
#pragma unroll
    for (int j = 0; j < 8; ++j)
#pragma unroll
      for (int q = 0; q < 4; ++q) {
        const int row = bm + w * 32 + i * 16 + g * 4 + q;
        const int dd = dbase + j * 16 + r;
        Cb[((size_t)hh * N + row) * DHEAD + dd] = __float2bfloat16(acc[i][j][q]);
      }
}

// ---- el/er from xb and projected attn vectors: el[n,h] = xb[n,:]·al2[h,:] --
__global__ __launch_bounds__(256) void elr2_kernel(const bf16* __restrict__ xb,
                                                   const float* __restrict__ alr2,
                                                   float* __restrict__ el,
                                                   float* __restrict__ er) {
  __shared__ float alrs[2048];
  const int t = threadIdx.x;
  for (int i = t; i < 2048; i += 256) alrs[i] = alr2[i];
  __syncthreads();
  const int wv = t >> 6, lane = t & 63;
  const int n = blockIdx.x * 4 + wv;
  const uint2 v2 = *reinterpret_cast<const uint2*>(&xb[(size_t)n * HID + lane * 4]);
  const float xf[4] = {bflo(v2.x), bfhi(v2.x), bflo(v2.y), bfhi(v2.y)};
  float pl[4], pr[4];
#pragma unroll
  for (int hh = 0; hh < 4; ++hh) {
    const int base = hh * 256 + lane * 4;
    pl[hh] = xf[0] * alrs[base] + xf[1] * alrs[base + 1] +
             xf[2] * alrs[base + 2] + xf[3] * alrs[base + 3];
    pr[hh] = xf[0] * alrs[1024 + base] + xf[1] * alrs[1024 + base + 1] +
             xf[2] * alrs[1024 + base + 2] + xf[3] * alrs[1024 + base + 3];
  }
  for (int off = 32; off; off >>= 1) {
#pragma unroll
    for (int hh = 0; hh < 4; ++hh) {
      pl[hh] += __shfl_xor(pl[hh], off);
      pr[hh] += __shfl_xor(pr[hh], off);
    }
  }
  if (lane == 0) {
#pragma unroll
    for (int hh = 0; hh < 4; ++hh) {
      el[n * HEADS + hh] = pl[hh];
      er[n * HEADS + hh] = pr[hh];
    }
  }
}

// ---- agg: one WAVE per (column, head); head = blockIdx&3 -> XCD affinity ---
// featb head-major: each head's 2MB slab served by 2 XCDs' L2s. All LDS state
// is wave-private -> no block barriers at all. Gather 4-deep unrolled.
__global__ __launch_bounds__(256) void agg_kernel(const int* __restrict__ colcnt,
                                                  const int* __restrict__ colsrc,
                                                  const float* __restrict__ el,
                                                  const float* __restrict__ er,
                                                  const bf16* __restrict__ featb,
                                                  const float* __restrict__ bias,
                                                  float* __restrict__ out) {
  __shared__ int tmp[4][CAPC];
  __shared__ int slist[4][CAPC];
  __shared__ float pbuf[4][CAPC];
  const int t = threadIdx.x;
  const int grp = t >> 6;   // wave id = column slot
  const int lane = t & 63;
  const int h = blockIdx.x & 3;                 // head (XCD-affine)
  const int d = (blockIdx.x >> 2) * 4 + grp;    // destination column
  const int C = min(colcnt[d], CAPC);
  for (int i = lane; i < C; i += 64) tmp[grp][i] = colsrc[(size_t)d * CAPC + i];
  // wave-private LDS: in-order within wave, no barriers needed
  for (int i = lane; i < C; i += 64) {
    const int v = tmp[grp][i];
    int rk = 0;
    for (int j = 0; j < C; ++j) rk += (tmp[grp][j] < v);
    slist[grp][rk] = v;
  }
  const float er_dh = er[d * HEADS + h];
  float m = -INFINITY;
  for (int i = lane; i < C; i += 64) {
    float e = el[slist[grp][i] * HEADS + h] + er_dh;
    e = e >= 0.f ? e : 0.2f * e;
    pbuf[grp][i] = e;
    m = fmaxf(m, e);
  }
#pragma unroll
  for (int off = 32; off; off >>= 1) m = fmaxf(m, __shfl_xor(m, off));
  float dsum = 0.f;
  for (int i = lane; i < C; i += 64) {
    const float p = __expf(pbuf[grp][i] - m);
    pbuf[grp][i] = p;
    dsum += p;
  }
#pragma unroll
  for (int off = 32; off; off >>= 1) dsum += __shfl_xor(dsum, off);
  // gather: 64 lanes x 8B (uint2 = 4 bf16) = 512B per source row; 4-deep
  const bf16* fh = featb + (size_t)h * N * DHEAD;
  float a0 = 0.f, a1 = 0.f, a2 = 0.f, a3 = 0.f;
  int i = 0;
  for (; i + 4 <= C; i += 4) {
    const float p0 = pbuf[grp][i];
    const float p1 = pbuf[grp][i + 1];
    const float p2 = pbuf[grp][i + 2];
    const float p3 = pbuf[grp][i + 3];
    const uint2 v0 = *reinterpret_cast<const uint2*>(
        &fh[(size_t)slist[grp][i] * DHEAD + lane * 4]);
    const uint2 v1 = *reinterpret_cast<const uint2*>(
        &fh[(size_t)slist[grp][i + 1] * DHEAD + lane * 4]);
    const uint2 v2 = *reinterpret_cast<const uint2*>(
        &fh[(size_t)slist[grp][i + 2] * DHEAD + lane * 4]);
    const uint2 v3 = *reinterpret_cast<const uint2*>(
        &fh[(size_t)slist[grp][i + 3] * DHEAD + lane * 4]);
    a0 = fmaf(p0, bflo(v0.x), a0);
    a1 = fmaf(p0, bfhi(v0.x), a1);
    a2 = fmaf(p0, bflo(v0.y), a2);
    a3 = fmaf(p0, bfhi(v0.y), a3);
    a0 = fmaf(p1, bflo(v1.x), a0);
    a1 = fmaf(p1, bfhi(v1.x), a1);
    a2 = fmaf(p1, bflo(v1.y), a2);
    a3 = fmaf(p1, bfhi(v1.y), a3);
    a0 = fmaf(p2, bflo(v2.x), a0);
    a1 = fmaf(p2, bfhi(v2.x), a1);
    a2 = fmaf(p2, bflo(v2.y), a2);
    a3 = fmaf(p2, bfhi(v2.y), a3);
    a0 = fmaf(p3, bflo(v3.x), a0);
    a1 = fmaf(p3, bfhi(v3.x), a1);
    a2 = fmaf(p3, bflo(v3.y), a2);
    a3 = fmaf(p3, bfhi(v3.y), a3);
  }
  for (; i < C; ++i) {
    const float p0 = pbuf[grp][i];
    const uint2 v0 = *reinterpret_cast<const uint2*>(
        &fh[(size_t)slist[grp][i] * DHEAD + lane * 4]);
    a0 = fmaf(p0, bflo(v0.x), a0);
    a1 = fmaf(p0, bfhi(v0.x), a1);
    a2 = fmaf(p0, bflo(v0.y), a2);
    a3 = fmaf(p0, bfhi(v0.y), a3);
  }
  const float inv = C > 0 ? 1.f / dsum : 0.f;
  const int dbase = h * DHEAD + lane * 4;
  float o[4];
  o[0] = a0 * inv + bias[dbase + 0];
  o[1] = a1 * inv + bias[dbase + 1];
  o[2] = a2 * inv + bias[dbase + 2];
  o[3] = a3 * inv + bias[dbase + 3];
#pragma unroll
  for (int k = 0; k < 4; ++k) o[k] = o[k] > 0.f ? o[k] : expm1f(o[k]);
  *reinterpret_cast<float4*>(&out[(size_t)d * FOUT + dbase]) =
      make_float4(o[0], o[1], o[2], o[3]);
}

extern "C" void kernel_launch(void* const* d_in, const int* in_sizes, int n_in,
                              void* d_out, int out_size, void* d_ws, size_t ws_size,
                              hipStream_t stream) {
  const float* h        = (const float*)d_in[0];
  const float* simlar   = (const float*)d_in[1];
  const float* adj      = (const float*)d_in[2];
  const float* W_trans  = (const float*)d_in[3];
  const float* gat_W    = (const float*)d_in[4];
  const float* attn_l   = (const float*)d_in[5];
  const float* attn_r   = (const float*)d_in[6];
  const float* gat_bias = (const float*)d_in[7];
  // sem_W1 / sem_b1 / sem_W2 unused: beta = softmax over singleton == 1 -> out == sem.
  float* out = (float*)d_out;

  char* ws = (char*)d_ws;
  const size_t MB = 1 << 20;
  bf16* Wtb   = (bf16*)(ws);                    // 256 KB (HID x FIN)
  bf16* gWtb  = (bf16*)(ws + 512 * 1024);       // 512 KB (FOUT x HID)
  bf16* xb    = (bf16*)(ws + 1 * MB);           // 2 MB   (N x HID)
  float* el   = (float*)(ws + 3 * MB);          // 64 KB
  float* er   = (float*)(ws + 3 * MB + 65536);  // 64 KB
  float* alr2 = (float*)(ws + 3 * MB + 131072); // 8 KB
  bf16* featb = (bf16*)(ws + 4 * MB);           // 8 MB   [4][N][256] head-major
  int* colcnt = (int*)(ws + 12 * MB);           // 16 KB
  int* colsrc = (int*)(ws + 13 * MB);           // 1.5 MB

  scan_kernel<<<N, 256, 0, stream>>>(W_trans, gat_W, attn_l, attn_r, adj, simlar,
                                     Wtb, gWtb, alr2, colcnt, colsrc);
  gemm_h<<<dim3(N / 64, HID / 64), 256, 0, stream>>>(h, Wtb, xb);
  gemm128<<<dim3(N / 128, FOUT / 128), 256, 0, stream>>>(xb, gWtb, featb);
  elr2_kernel<<<N / 4, 256, 0, stream>>>(xb, alr2, el, er);
  agg_kernel<<<N, 256, 0, stream>>>(colcnt, colsrc, el, er, featb, gat_bias, out);
}

// Round 14
// 64.876 us; speedup vs baseline: 1.3062x; 1.0212x over previous
//
#include <hip/hip_runtime.h>
#include <hip/hip_bf16.h>
#include <math.h>

#define N 4096
#define FIN 512
#define HID 256
#define HEADS 4
#define DHEAD 256
#define FOUT 1024
#define TOPK 29
#define CAP 64    // per-row candidate capacity (mean ~20.5, sd ~4.5)
#define CAPC 96   // per-column source capacity (in-degree mean ~20.4)

typedef __attribute__((ext_vector_type(8))) short short8;
typedef __attribute__((ext_vector_type(4))) float f32x4;
typedef __hip_bfloat16 bf16;

__device__ __forceinline__ float bflo(unsigned int u) {
  return __uint_as_float(u << 16);
}
__device__ __forceinline__ float bfhi(unsigned int u) {
  return __uint_as_float(u & 0xffff0000u);
}

// ---- scan: phase0 prep (tiny, coalesced) + block-per-row scan + top-29 -----
// Phase 1 restructured: issue ALL conditional sim loads before ANY use, so the
// ~700cy HBM latencies overlap instead of serializing (was: load/use per group).
__global__ __launch_bounds__(256) void scan_kernel(
    const float* __restrict__ W_trans, const float* __restrict__ gat_W,
    const float* __restrict__ attn_l, const float* __restrict__ attn_r,
    const float* __restrict__ adj, const float* __restrict__ simlar,
    bf16* __restrict__ Wtb, bf16* __restrict__ gWtb,
    float* __restrict__ alr2, int* __restrict__ colcnt,
    int* __restrict__ colsrc) {
  const int t = threadIdx.x, s = blockIdx.x;
  // ---- phase 0 ----
  {
    const int S1 = 4096;
    const int S2 = S1 + HID * FIN / 4;          // 36864
    const int S3 = S2 + FOUT * HID / 4;         // 102400
    const int TOT = S3 + 2 * HEADS * HID * 16;  // 135168
    const int i = s * 256 + t;  // grid covers 1M slots > TOT: single pass
    if (i < TOT) {
      if (i < S1) {
        colcnt[i] = 0;
      } else if (i < S2) {
        const int j4 = i - S1;
        const float4 v = reinterpret_cast<const float4*>(W_trans)[j4];
        const int k = j4 >> 6;          // fin row 0..511
        const int c0 = (j4 & 63) * 4;   // hid col 0..255
        Wtb[(size_t)(c0 + 0) * FIN + k] = __float2bfloat16(v.x);
        Wtb[(size_t)(c0 + 1) * FIN + k] = __float2bfloat16(v.y);
        Wtb[(size_t)(c0 + 2) * FIN + k] = __float2bfloat16(v.z);
        Wtb[(size_t)(c0 + 3) * FIN + k] = __float2bfloat16(v.w);
      } else if (i < S3) {
        const int j4 = i - S2;
        const float4 v = reinterpret_cast<const float4*>(gat_W)[j4];
        const int k = j4 >> 8;          // hid row 0..255
        const int c0 = (j4 & 255) * 4;  // fout col 0..1023
        gWtb[(size_t)(c0 + 0) * HID + k] = __float2bfloat16(v.x);
        gWtb[(size_t)(c0 + 1) * HID + k] = __float2bfloat16(v.y);
        gWtb[(size_t)(c0 + 2) * HID + k] = __float2bfloat16(v.z);
        gWtb[(size_t)(c0 + 3) * HID + k] = __float2bfloat16(v.w);
      } else {
        const int u = i - S3;
        const int j = u >> 4, l16 = u & 15;
        const float* vec = (j < 1024) ? attn_l : attn_r;
        const int jj = j & 1023;
        const int hh = jj >> 8, k = jj & 255;
        const float4* wp = reinterpret_cast<const float4*>(
            &gat_W[(size_t)k * FOUT + hh * DHEAD + l16 * 16]);
        const float4* vp = reinterpret_cast<const float4*>(&vec[hh * DHEAD + l16 * 16]);
        float acc = 0.f;
#pragma unroll
        for (int q = 0; q < 4; ++q) {
          const float4 w4 = wp[q], v4 = vp[q];
          acc += w4.x * v4.x + w4.y * v4.y + w4.z * v4.z + w4.w * v4.w;
        }
#pragma unroll
        for (int off = 1; off < 16; off <<= 1) acc += __shfl_xor(acc, off);
        if (l16 == 0) alr2[j] = acc;
      }
    }
  }
  // ---- phase 1: scan row s ----
  __shared__ float swv[CAP];
  __shared__ int swi[CAP];
  __shared__ int cnt;
  if (t == 0) cnt = 0;
  __syncthreads();
  const uint4* rowadj = reinterpret_cast<const uint4*>(adj + (size_t)s * N);
  const float4* rowsim = reinterpret_cast<const float4*>(simlar + (size_t)s * N);
  uint4 a[4];
#pragma unroll
  for (int q = 0; q < 4; ++q) a[q] = rowadj[q * 256 + t];  // 4 loads in flight
  bool ghit[4];
#pragma unroll
  for (int q = 0; q < 4; ++q) ghit[q] = (a[q].x | a[q].y | a[q].z | a[q].w) != 0;
  // issue ALL conditional sim loads (exec-masked, independent -> overlap)
  float4 sv[4];
#pragma unroll
  for (int q = 0; q < 4; ++q) {
    if (ghit[q]) sv[q] = rowsim[q * 256 + t];
  }
  // now consume
#pragma unroll
  for (int q = 0; q < 4; ++q) {
    if (ghit[q]) {
      const int j = q * 256 + t;
      const unsigned aw[4] = {a[q].x, a[q].y, a[q].z, a[q].w};
      const float ss[4] = {sv[q].x, sv[q].y, sv[q].z, sv[q].w};
#pragma unroll
      for (int c = 0; c < 4; ++c) {
        if (aw[c] && ss[c] > 0.f) {
          const int p = atomicAdd(&cnt, 1);
          if (p < CAP) {
            swv[p] = ss[c];
            swi[p] = j * 4 + c;
          }
        }
      }
    }
  }
  __syncthreads();
  // ---- phase 2: rank select (value-based, order-independent) ----
  const int C = min(cnt, CAP);
  if (t < C) {
    const float x = swv[t];
    int rk = 0;
    for (int jj = 0; jj < C; ++jj) rk += (swv[jj] > x);
    if (rk < TOPK) {
      const int d = swi[t];
      const int p = atomicAdd(&colcnt[d], 1);
      if (p < CAPC) colsrc[(size_t)d * CAPC + p] = s;
    }
  }
}

// ------- GEMM1 (64x64, BK=64): xb = lrelu(h_f32 @ Wtb^T), cvt in staging ----
__global__ __launch_bounds__(256) void gemm_h(const float* __restrict__ A,
                                              const bf16* __restrict__ Bt,
                                              bf16* __restrict__ Cb) {
  __shared__ bf16 As[64][72];  // +8 pad
  __shared__ bf16 Bs[64][72];
  const int t = threadIdx.x;
  const int bm = blockIdx.x * 64, bn = blockIdx.y * 64;
  const int w = t >> 6, lane = t & 63, r = lane & 15, g = lane >> 4;
  const int m = t >> 2;
  const int fb = (t & 3) * 16;  // 16 floats per thread per row-quarter
  const int c0 = (t & 3) * 8;   // B staging chunks
  f32x4 acc[4] = {};
  for (int k0 = 0; k0 < FIN; k0 += 64) {
    {  // A: fp32 -> bf16 convert into LDS
      const float4* hp = reinterpret_cast<const float4*>(&A[(size_t)(bm + m) * FIN + k0 + fb]);
      const float4 f0 = hp[0], f1 = hp[1], f2 = hp[2], f3 = hp[3];
      bf16 ta[16];
      ta[0] = __float2bfloat16(f0.x); ta[1] = __float2bfloat16(f0.y);
      ta[2] = __float2bfloat16(f0.z); ta[3] = __float2bfloat16(f0.w);
      ta[4] = __float2bfloat16(f1.x); ta[5] = __float2bfloat16(f1.y);
      ta[6] = __float2bfloat16(f1.z); ta[7] = __float2bfloat16(f1.w);
      ta[8] = __float2bfloat16(f2.x); ta[9] = __float2bfloat16(f2.y);
      ta[10] = __float2bfloat16(f2.z); ta[11] = __float2bfloat16(f2.w);
      ta[12] = __float2bfloat16(f3.x); ta[13] = __float2bfloat16(f3.y);
      ta[14] = __float2bfloat16(f3.z); ta[15] = __float2bfloat16(f3.w);
      *reinterpret_cast<int4*>(&As[m][fb]) = *reinterpret_cast<int4*>(&ta[0]);
      *reinterpret_cast<int4*>(&As[m][fb + 8]) = *reinterpret_cast<int4*>(&ta[8]);
    }
    {  // B: bf16 direct
      const bf16* brow = &Bt[(size_t)(bn + m) * FIN + k0];
      *reinterpret_cast<int4*>(&Bs[m][c0]) = *reinterpret_cast<const int4*>(&brow[c0]);
      *reinterpret_cast<int4*>(&Bs[m][c0 + 32]) = *reinterpret_cast<const int4*>(&brow[c0 + 32]);
    }
    __syncthreads();
    const short8 a0 = *reinterpret_cast<short8*>(&As[w * 16 + r][g * 8]);
    const short8 a1 = *reinterpret_cast<short8*>(&As[w * 16 + r][32 + g * 8]);
#pragma unroll
    for (int j = 0; j < 4; ++j) {
      const short8 b0 = *reinterpret_cast<short8*>(&Bs[j * 16 + r][g * 8]);
      const short8 b1 = *reinterpret_cast<short8*>(&Bs[j * 16 + r][32 + g * 8]);
      acc[j] = __builtin_amdgcn_mfma_f32_16x16x32_bf16(a0, b0, acc[j], 0, 0, 0);
      acc[j] = __builtin_amdgcn_mfma_f32_16x16x32_bf16(a1, b1, acc[j], 0, 0, 0);
    }
    __syncthreads();
  }
#pragma unroll
  for (int j = 0; j < 4; ++j)
#pragma unroll
    for (int q = 0; q < 4; ++q) {
      const int row = bm + w * 16 + g * 4 + q;
      const int col = bn + j * 16 + r;
      float v = acc[j][q];
      v = v >= 0.f ? v : 0.01f * v;  // lrelu(0.01)
      Cb[(size_t)row * HID + col] = __float2bfloat16(v);
    }
}

// ------- GEMM2 (128x128, BK=64): featb_hm[h][n][d] = (xb @ gWtb^T) ----------
// Output stored HEAD-MAJOR [4][N][256] so agg's per-head gather is L2-local.
__global__ __launch_bounds__(256) void gemm128(const bf16* __restrict__ A,
                                               const bf16* __restrict__ Bt,
                                               bf16* __restrict__ Cb) {
  __shared__ bf16 As[128][72];  // +8 pad
  __shared__ bf16 Bs[128][72];
  const int t = threadIdx.x;
  const int bm = blockIdx.x * 128, bn = blockIdx.y * 128;
  const int w = t >> 6, lane = t & 63, r = lane & 15, g = lane >> 4;
  const int m = t >> 1, cb = (t & 1) * 32;
  f32x4 acc[2][8] = {};
  for (int k0 = 0; k0 < HID; k0 += 64) {
    const bf16* arow = &A[(size_t)(bm + m) * HID + k0 + cb];
    const bf16* brow = &Bt[(size_t)(bn + m) * HID + k0 + cb];
#pragma unroll
    for (int q = 0; q < 4; ++q) {
      *reinterpret_cast<int4*>(&As[m][cb + q * 8]) =
          *reinterpret_cast<const int4*>(&arow[q * 8]);
      *reinterpret_cast<int4*>(&Bs[m][cb + q * 8]) =
          *reinterpret_cast<const int4*>(&brow[q * 8]);
    }
    __syncthreads();
    const short8 a00 = *reinterpret_cast<short8*>(&As[w * 32 + r][g * 8]);
    const short8 a01 = *reinterpret_cast<short8*>(&As[w * 32 + r][32 + g * 8]);
    const short8 a10 = *reinterpret_cast<short8*>(&As[w * 32 + 16 + r][g * 8]);
    const short8 a11 = *reinterpret_cast<short8*>(&As[w * 32 + 16 + r][32 + g * 8]);
#pragma unroll
    for (int j = 0; j < 8; ++j) {
      const short8 b0 = *reinterpret_cast<short8*>(&Bs[j * 16 + r][g * 8]);
      const short8 b1 = *reinterpret_cast<short8*>(&Bs[j * 16 + r][32 + g * 8]);
      acc[0][j] = __builtin_amdgcn_mfma_f32_16x16x32_bf16(a00, b0, acc[0][j], 0, 0, 0);
      acc[0][j] = __builtin_amdgcn_mfma_f32_16x16x32_bf16(a01, b1, acc[0][j], 0, 0, 0);
      acc[1][j] = __builtin_amdgcn_mfma_f32_16x16x32_bf16(a10, b0, acc[1][j], 0, 0, 0);
      acc[1][j] = __builtin_amdgcn_mfma_f32_16x16x32_bf16(a11, b1, acc[1][j], 0, 0, 0);
    }
    __syncthreads();
  }
  const int hh = bn >> 8;          // head (constant per block; bn%128==0)
  const int dbase = bn & 255;      // dim offset within head
#pragma unroll
  for (int i = 0; i < 2; ++i)
#pragma unroll
    for (int j = 0; j < 8; ++j)
#pragma unroll
      for (int q = 0; q < 4; ++q) {
        const int row = bm + w * 32 + i * 16 + g * 4 + q;
        const int dd = dbase + j * 16 + r;
        Cb[((size_t)hh * N + row) * DHEAD + dd] = __float2bfloat16(acc[i][j][q]);
      }
}

// ---- el/er from xb and projected attn vectors: el[n,h] = xb[n,:]·al2[h,:] --
__global__ __launch_bounds__(256) void elr2_kernel(const bf16* __restrict__ xb,
                                                   const float* __restrict__ alr2,
                                                   float* __restrict__ el,
                                                   float* __restrict__ er) {
  __shared__ float alrs[2048];
  const int t = threadIdx.x;
  for (int i = t; i < 2048; i += 256) alrs[i] = alr2[i];
  __syncthreads();
  const int wv = t >> 6, lane = t & 63;
  const int n = blockIdx.x * 4 + wv;
  const uint2 v2 = *reinterpret_cast<const uint2*>(&xb[(size_t)n * HID + lane * 4]);
  const float xf[4] = {bflo(v2.x), bfhi(v2.x), bflo(v2.y), bfhi(v2.y)};
  float pl[4], pr[4];
#pragma unroll
  for (int hh = 0; hh < 4; ++hh) {
    const int base = hh * 256 + lane * 4;
    pl[hh] = xf[0] * alrs[base] + xf[1] * alrs[base + 1] +
             xf[2] * alrs[base + 2] + xf[3] * alrs[base + 3];
    pr[hh] = xf[0] * alrs[1024 + base] + xf[1] * alrs[1024 + base + 1] +
             xf[2] * alrs[1024 + base + 2] + xf[3] * alrs[1024 + base + 3];
  }
  for (int off = 32; off; off >>= 1) {
#pragma unroll
    for (int hh = 0; hh < 4; ++hh) {
      pl[hh] += __shfl_xor(pl[hh], off);
      pr[hh] += __shfl_xor(pr[hh], off);
    }
  }
  if (lane == 0) {
#pragma unroll
    for (int hh = 0; hh < 4; ++hh) {
      el[n * HEADS + hh] = pl[hh];
      er[n * HEADS + hh] = pr[hh];
    }
  }
}

// ---- agg: one WAVE per (column, head); head = blockIdx&3 -> XCD affinity ---
__global__ __launch_bounds__(256) void agg_kernel(const int* __restrict__ colcnt,
                                                  const int* __restrict__ colsrc,
                                                  const float* __restrict__ el,
                                                  const float* __restrict__ er,
                                                  const bf16* __restrict__ featb,
                                                  const float* __restrict__ bias,
                                                  float* __restrict__ out) {
  __shared__ int tmp[4][CAPC];
  __shared__ int slist[4][CAPC];
  __shared__ float pbuf[4][CAPC];
  const int t = threadIdx.x;
  const int grp = t >> 6;   // wave id = column slot
  const int lane = t & 63;
  const int h = blockIdx.x & 3;                 // head (XCD-affine)
  const int d = (blockIdx.x >> 2) * 4 + grp;    // destination column
  const int C = min(colcnt[d], CAPC);
  for (int i = lane; i < C; i += 64) tmp[grp][i] = colsrc[(size_t)d * CAPC + i];
  // wave-private LDS: in-order within wave, no barriers needed
  for (int i = lane; i < C; i += 64) {
    const int v = tmp[grp][i];
    int rk = 0;
    for (int j = 0; j < C; ++j) rk += (tmp[grp][j] < v);
    slist[grp][rk] = v;
  }
  const float er_dh = er[d * HEADS + h];
  float m = -INFINITY;
  for (int i = lane; i < C; i += 64) {
    float e = el[slist[grp][i] * HEADS + h] + er_dh;
    e = e >= 0.f ? e : 0.2f * e;
    pbuf[grp][i] = e;
    m = fmaxf(m, e);
  }
#pragma unroll
  for (int off = 32; off; off >>= 1) m = fmaxf(m, __shfl_xor(m, off));
  float dsum = 0.f;
  for (int i = lane; i < C; i += 64) {
    const float p = __expf(pbuf[grp][i] - m);
    pbuf[grp][i] = p;
    dsum += p;
  }
#pragma unroll
  for (int off = 32; off; off >>= 1) dsum += __shfl_xor(dsum, off);
  // gather: 64 lanes x 8B (uint2 = 4 bf16) = 512B per source row; 4-deep
  const bf16* fh = featb + (size_t)h * N * DHEAD;
  float a0 = 0.f, a1 = 0.f, a2 = 0.f, a3 = 0.f;
  int i = 0;
  for (; i + 4 <= C; i += 4) {
    const float p0 = pbuf[grp][i];
    const float p1 = pbuf[grp][i + 1];
    const float p2 = pbuf[grp][i + 2];
    const float p3 = pbuf[grp][i + 3];
    const uint2 v0 = *reinterpret_cast<const uint2*>(
        &fh[(size_t)slist[grp][i] * DHEAD + lane * 4]);
    const uint2 v1 = *reinterpret_cast<const uint2*>(
        &fh[(size_t)slist[grp][i + 1] * DHEAD + lane * 4]);
    const uint2 v2 = *reinterpret_cast<const uint2*>(
        &fh[(size_t)slist[grp][i + 2] * DHEAD + lane * 4]);
    const uint2 v3 = *reinterpret_cast<const uint2*>(
        &fh[(size_t)slist[grp][i + 3] * DHEAD + lane * 4]);
    a0 = fmaf(p0, bflo(v0.x), a0);
    a1 = fmaf(p0, bfhi(v0.x), a1);
    a2 = fmaf(p0, bflo(v0.y), a2);
    a3 = fmaf(p0, bfhi(v0.y), a3);
    a0 = fmaf(p1, bflo(v1.x), a0);
    a1 = fmaf(p1, bfhi(v1.x), a1);
    a2 = fmaf(p1, bflo(v1.y), a2);
    a3 = fmaf(p1, bfhi(v1.y), a3);
    a0 = fmaf(p2, bflo(v2.x), a0);
    a1 = fmaf(p2, bfhi(v2.x), a1);
    a2 = fmaf(p2, bflo(v2.y), a2);
    a3 = fmaf(p2, bfhi(v2.y), a3);
    a0 = fmaf(p3, bflo(v3.x), a0);
    a1 = fmaf(p3, bfhi(v3.x), a1);
    a2 = fmaf(p3, bflo(v3.y), a2);
    a3 = fmaf(p3, bfhi(v3.y), a3);
  }
  for (; i < C; ++i) {
    const float p0 = pbuf[grp][i];
    const uint2 v0 = *reinterpret_cast<const uint2*>(
        &fh[(size_t)slist[grp][i] * DHEAD + lane * 4]);
    a0 = fmaf(p0, bflo(v0.x), a0);
    a1 = fmaf(p0, bfhi(v0.x), a1);
    a2 = fmaf(p0, bflo(v0.y), a2);
    a3 = fmaf(p0, bfhi(v0.y), a3);
  }
  const float inv = C > 0 ? 1.f / dsum : 0.f;
  const int dbase = h * DHEAD + lane * 4;
  float o[4];
  o[0] = a0 * inv + bias[dbase + 0];
  o[1] = a1 * inv + bias[dbase + 1];
  o[2] = a2 * inv + bias[dbase + 2];
  o[3] = a3 * inv + bias[dbase + 3];
#pragma unroll
  for (int k = 0; k < 4; ++k) o[k] = o[k] > 0.f ? o[k] : expm1f(o[k]);
  *reinterpret_cast<float4*>(&out[(size_t)d * FOUT + dbase]) =
      make_float4(o[0], o[1], o[2], o[3]);
}

extern "C" void kernel_launch(void* const* d_in, const int* in_sizes, int n_in,
                              void* d_out, int out_size, void* d_ws, size_t ws_size,
                              hipStream_t stream) {
  const float* h        = (const float*)d_in[0];
  const float* simlar   = (const float*)d_in[1];
  const float* adj      = (const float*)d_in[2];
  const float* W_trans  = (const float*)d_in[3];
  const float* gat_W    = (const float*)d_in[4];
  const float* attn_l   = (const float*)d_in[5];
  const float* attn_r   = (const float*)d_in[6];
  const float* gat_bias = (const float*)d_in[7];
  // sem_W1 / sem_b1 / sem_W2 unused: beta = softmax over singleton == 1 -> out == sem.
  float* out = (float*)d_out;

  char* ws = (char*)d_ws;
  const size_t MB = 1 << 20;
  bf16* Wtb   = (bf16*)(ws);                    // 256 KB (HID x FIN)
  bf16* gWtb  = (bf16*)(ws + 512 * 1024);       // 512 KB (FOUT x HID)
  bf16* xb    = (bf16*)(ws + 1 * MB);           // 2 MB   (N x HID)
  float* el   = (float*)(ws + 3 * MB);          // 64 KB
  float* er   = (float*)(ws + 3 * MB + 65536);  // 64 KB
  float* alr2 = (float*)(ws + 3 * MB + 131072); // 8 KB
  bf16* featb = (bf16*)(ws + 4 * MB);           // 8 MB   [4][N][256] head-major
  int* colcnt = (int*)(ws + 12 * MB);           // 16 KB
  int* colsrc = (int*)(ws + 13 * MB);           // 1.5 MB

  scan_kernel<<<N, 256, 0, stream>>>(W_trans, gat_W, attn_l, attn_r, adj, simlar,
                                     Wtb, gWtb, alr2, colcnt, colsrc);
  gemm_h<<<dim3(N / 64, HID / 64), 256, 0, stream>>>(h, Wtb, xb);
  gemm128<<<dim3(N / 128, FOUT / 128), 256, 0, stream>>>(xb, gWtb, featb);
  elr2_kernel<<<N / 4, 256, 0, stream>>>(xb, alr2, el, er);
  agg_kernel<<<N, 256, 0, stream>>>(colcnt, colsrc, el, er, featb, gat_bias, out);
}